// Round 9
// baseline (510.571 us; speedup 1.0000x reference)
//
#include <hip/hip_runtime.h>
#include <hip/hip_bf16.h>
#include <hip/hip_fp16.h>
#include <math.h>

#define NHID 128
#define NCLASS 40
#define NBLK 256          // edge-chunk blocks for bucket passes
#define MAXBUK 1600       // >= ceil(N/64)

typedef _Float16 f16;
typedef f16 f16x8 __attribute__((ext_vector_type(8)));
typedef float f32x4 __attribute__((ext_vector_type(4)));

// ---------------- CSR build: 2-level counting sort (LDS atomics only) ----
// eb entries packed: (src << 6) | (dst & 63)

__global__ __launch_bounds__(256) void bucket_hist(const int* __restrict__ dst,
                                                   int* __restrict__ bh,
                                                   int E, int nbuk, int chunk) {
    __shared__ int h[MAXBUK];
    for (int i = threadIdx.x; i < nbuk; i += 256) h[i] = 0;
    __syncthreads();
    int b = blockIdx.x;
    int lo = b * chunk, hi = min(E, lo + chunk);
    for (int e = lo + threadIdx.x; e < hi; e += 256) atomicAdd(&h[dst[e] >> 6], 1);
    __syncthreads();
    for (int i = threadIdx.x; i < nbuk; i += 256) bh[(size_t)b * nbuk + i] = h[i];
}

__global__ __launch_bounds__(256) void bucket_total(const int* __restrict__ bh,
                                                    int* __restrict__ T, int nbuk) {
    int buk = blockIdx.x * 256 + threadIdx.x;
    if (buk >= nbuk) return;
    int s = 0;
    for (int b = 0; b < NBLK; ++b) s += bh[(size_t)b * nbuk + buk];
    T[buk] = s;
}

__global__ __launch_bounds__(256) void bucket_scan(const int* __restrict__ T,
                                                   int* __restrict__ BB, int nbuk, int E) {
    __shared__ int sc[256];
    __shared__ int carry;
    if (threadIdx.x == 0) carry = 0;
    __syncthreads();
    for (int base = 0; base < nbuk; base += 256) {
        int i = base + threadIdx.x;
        int v = (i < nbuk) ? T[i] : 0;
        sc[threadIdx.x] = v;
        __syncthreads();
        for (int off = 1; off < 256; off <<= 1) {
            int t = (threadIdx.x >= off) ? sc[threadIdx.x - off] : 0;
            __syncthreads();
            sc[threadIdx.x] += t;
            __syncthreads();
        }
        if (i < nbuk) BB[i] = carry + sc[threadIdx.x] - v;
        __syncthreads();
        if (threadIdx.x == 255) carry += sc[255];
        __syncthreads();
    }
    if (threadIdx.x == 0) BB[nbuk] = E;
}

__global__ __launch_bounds__(256) void bucket_expand(const int* __restrict__ bh,
                                                     const int* __restrict__ BB,
                                                     int* __restrict__ off, int nbuk) {
    int buk = blockIdx.x * 256 + threadIdx.x;
    if (buk >= nbuk) return;
    int run = BB[buk];
    for (int b = 0; b < NBLK; ++b) {
        off[(size_t)b * nbuk + buk] = run;
        run += bh[(size_t)b * nbuk + buk];
    }
}

__global__ __launch_bounds__(256) void bucket_scatter(const int* __restrict__ src,
                                                      const int* __restrict__ dst,
                                                      const int* __restrict__ off,
                                                      int* __restrict__ eb,
                                                      int E, int nbuk, int chunk) {
    __shared__ int cur[MAXBUK];
    int b = blockIdx.x;
    for (int i = threadIdx.x; i < nbuk; i += 256) cur[i] = off[(size_t)b * nbuk + i];
    __syncthreads();
    int lo = b * chunk, hi = min(E, lo + chunk);
    for (int e = lo + threadIdx.x; e < hi; e += 256) {
        int d = dst[e], s = src[e];
        int pos = atomicAdd(&cur[d >> 6], 1);
        eb[pos] = (s << 6) | (d & 63);
    }
}

__global__ __launch_bounds__(256) void bucket_csr(const int* __restrict__ eb,
                                                  const int* __restrict__ BB,
                                                  int* __restrict__ startA,
                                                  float* __restrict__ dinv,
                                                  int* __restrict__ col,
                                                  int N, int E) {
    __shared__ int h[64];
    int b = blockIdx.x;
    int bs = BB[b], be = BB[b + 1];
    if (threadIdx.x < 64) h[threadIdx.x] = 0;
    __syncthreads();
    for (int i = bs + threadIdx.x; i < be; i += 256) atomicAdd(&h[eb[i] & 63], 1);
    __syncthreads();
    if (threadIdx.x < 64) {  // wave 0
        int v = h[threadIdx.x];
        int incl = v;
#pragma unroll
        for (int o = 1; o < 64; o <<= 1) {
            int t = __shfl_up(incl, o, 64);
            if ((int)threadIdx.x >= o) incl += t;
        }
        int n = (b << 6) + threadIdx.x;
        if (n < N) {
            startA[n] = bs + incl - v;
            dinv[n] = rsqrtf((float)(v + 1));  // +1 self-loop
        }
        h[threadIdx.x] = incl - v;  // reuse as cursor
    }
    __syncthreads();
    for (int i = bs + threadIdx.x; i < be; i += 256) {
        int pk = eb[i];
        int pos = bs + atomicAdd(&h[pk & 63], 1);
        col[pos] = pk >> 6;
    }
    if (b == 0 && threadIdx.x == 0) startA[N] = E;
}

// --------------------------- MFMA GEMM ----------------------------------
// C = dinv[row] * (A @ W), fp16 out. ASLICE: A is slice-major f16
// [k/16][node][16]. CSLICE: C written slice-major [n/16][node][16].
template <int K, int BM, int BN, int WM, int WN, bool GUARDN, bool ASLICE, bool CSLICE>
__global__ __launch_bounds__(256) void gemm_mfma(const void* __restrict__ Ap,
                                                 const float* __restrict__ W,
                                                 const float* __restrict__ dinv,
                                                 f16* __restrict__ C, int M, int N) {
    constexpr int KC = 64;
    __shared__ f16 As[BM * KC];
    __shared__ f16 Bs[BN * KC];
    __shared__ float sdinv[BM];
    const int t = threadIdx.x;
    const int wid = t >> 6, lane = t & 63;
    const int wm = wid % WM, wn = wid / WM;
    const int row0 = blockIdx.x * BM;
    const size_t SL = (size_t)M * 16;

    for (int i = t; i < BM; i += 256) {
        int r = row0 + i;
        sdinv[i] = dinv[r < M ? r : M - 1];
    }

    f32x4 acc[4][4] = {};

    for (int k0 = 0; k0 < K; k0 += KC) {
        if (ASLICE) {
            const f16* A = (const f16*)Ap;
#pragma unroll
            for (int i = 0; i < BM / 64; ++i) {
                int g = t + i * 256;          // 0 .. BM*4-1
                int sl = g / BM;              // 0..3 (16-col slice within K-step)
                int r = g % BM;
                int grow = row0 + r; if (grow >= M) grow = M - 1;
                const f16* sp = &A[(size_t)(k0 / 16 + sl) * SL + (size_t)grow * 16];
                f16x8 v0 = *reinterpret_cast<const f16x8*>(sp);
                f16x8 v1 = *reinterpret_cast<const f16x8*>(sp + 8);
                int c0 = sl * 2, c1 = sl * 2 + 1;
                *reinterpret_cast<f16x8*>(&As[r * 64 + ((c0 ^ (r & 7)) << 3)]) = v0;
                *reinterpret_cast<f16x8*>(&As[r * 64 + ((c1 ^ (r & 7)) << 3)]) = v1;
            }
        } else {
            const float* A = (const float*)Ap;
#pragma unroll
            for (int i = 0; i < BM / 32; ++i) {
                int g = t + i * 256;
                int r = g >> 3, c = g & 7;
                int grow = row0 + r; if (grow >= M) grow = M - 1;
                const float* s = &A[(size_t)grow * K + k0 + c * 8];
                float4 a = *reinterpret_cast<const float4*>(s);
                float4 b = *reinterpret_cast<const float4*>(s + 4);
                f16x8 v = {(f16)a.x, (f16)a.y, (f16)a.z, (f16)a.w,
                           (f16)b.x, (f16)b.y, (f16)b.z, (f16)b.w};
                *reinterpret_cast<f16x8*>(&As[r * 64 + ((c ^ (r & 7)) << 3)]) = v;
            }
        }
        if (!GUARDN) {
#pragma unroll
            for (int i = 0; i < BN / 16; ++i) {
                int v = t + i * 256;
                int kk = v / (BN / 4), nq = v % (BN / 4);
                float4 w = *reinterpret_cast<const float4*>(&W[(size_t)(k0 + kk) * N + nq * 4]);
                float ws[4] = {w.x, w.y, w.z, w.w};
#pragma unroll
                for (int j = 0; j < 4; ++j) {
                    int n = nq * 4 + j;
                    Bs[n * 64 + (((kk >> 3) ^ (n & 7)) << 3) + (kk & 7)] = (f16)ws[j];
                }
            }
        } else {
#pragma unroll
            for (int i = 0; i < BN / 16; ++i) {
                int v = t + i * 256;
                int kk = v / (BN / 4), nq = v % (BN / 4);
#pragma unroll
                for (int j = 0; j < 4; ++j) {
                    int n = nq * 4 + j;
                    float wv = (n < N) ? W[(size_t)(k0 + kk) * N + n] : 0.f;
                    Bs[n * 64 + (((kk >> 3) ^ (n & 7)) << 3) + (kk & 7)] = (f16)wv;
                }
            }
        }
        __syncthreads();

#pragma unroll
        for (int s = 0; s < 2; ++s) {
            f16x8 af[4], bf[4];
            int c = s * 4 + (lane >> 4);
#pragma unroll
            for (int mf = 0; mf < 4; ++mf) {
                int r = wm * 64 + mf * 16 + (lane & 15);
                af[mf] = *reinterpret_cast<const f16x8*>(&As[r * 64 + ((c ^ (r & 7)) << 3)]);
            }
#pragma unroll
            for (int nf = 0; nf < 4; ++nf) {
                int n = wn * 64 + nf * 16 + (lane & 15);
                bf[nf] = *reinterpret_cast<const f16x8*>(&Bs[n * 64 + ((c ^ (n & 7)) << 3)]);
            }
#pragma unroll
            for (int mf = 0; mf < 4; ++mf)
#pragma unroll
                for (int nf = 0; nf < 4; ++nf)
                    acc[mf][nf] = __builtin_amdgcn_mfma_f32_16x16x32_f16(af[mf], bf[nf],
                                                                         acc[mf][nf], 0, 0, 0);
        }
        __syncthreads();
    }

#pragma unroll
    for (int mf = 0; mf < 4; ++mf) {
#pragma unroll
        for (int q = 0; q < 4; ++q) {
            int lr = wm * 64 + mf * 16 + (lane >> 4) * 4 + q;
            int grow = row0 + lr;
            if (grow < M) {
                float scl = sdinv[lr];
#pragma unroll
                for (int nf = 0; nf < 4; ++nf) {
                    int gcol = wn * 64 + nf * 16 + (lane & 15);
                    if (CSLICE) {
                        C[(size_t)(gcol >> 4) * SL + (size_t)grow * 16 + (gcol & 15)] =
                            (f16)(acc[mf][nf][q] * scl);
                    } else if (!GUARDN || gcol < N) {
                        C[(size_t)grow * N + gcol] = (f16)(acc[mf][nf][q] * scl);
                    }
                }
            }
        }
    }
}

// --------------------------- Aggregation (slice-major) -------------------
// m stored [slice][node][16] f16, per-slice 3.2MB. slice = blockIdx&7 ->
// static round-robin dispatch pins slice s to XCD s; its L2 holds the slice
// (+dinv/start) < 4MB -> gathers are L2 hits. col/out streamed nontemporal.
// 8 lanes per node-walker (half2/lane), 32 walkers/block, 32 nodes/block.
__global__ __launch_bounds__(256) void agg_slice(
        const f16* __restrict__ m, const int* __restrict__ col,
        const int* __restrict__ start, const float* __restrict__ dinv,
        const float* __restrict__ bias, f16* __restrict__ outp, int N) {
    const int slice = blockIdx.x & 7;
    const int nb = blockIdx.x >> 3;
    const int walker = threadIdx.x >> 3;
    const int fl = threadIdx.x & 7;
    int n = nb * 32 + walker;
    if (n >= N) return;
    const size_t SL = (size_t)N * 16;
    const __half2* mp = reinterpret_cast<const __half2*>(m + slice * SL);
    const float2 b2 = *reinterpret_cast<const float2*>(&bias[slice * 16 + fl * 2]);
    int s = start[n], e = start[n + 1];
    float ax = 0.f, ay = 0.f, bx = 0.f, by = 0.f;
    float cx = 0.f, cy = 0.f, dx = 0.f, dy = 0.f;
    int p = s;
    for (; p + 4 <= e; p += 4) {
        int j0 = __builtin_nontemporal_load(&col[p]);
        int j1 = __builtin_nontemporal_load(&col[p + 1]);
        int j2 = __builtin_nontemporal_load(&col[p + 2]);
        int j3 = __builtin_nontemporal_load(&col[p + 3]);
        __half2 v0 = mp[(size_t)j0 * 8 + fl];
        __half2 v1 = mp[(size_t)j1 * 8 + fl];
        __half2 v2 = mp[(size_t)j2 * 8 + fl];
        __half2 v3 = mp[(size_t)j3 * 8 + fl];
        float2 f0 = __half22float2(v0), f1 = __half22float2(v1);
        float2 f2 = __half22float2(v2), f3 = __half22float2(v3);
        ax += f0.x; ay += f0.y; bx += f1.x; by += f1.y;
        cx += f2.x; cy += f2.y; dx += f3.x; dy += f3.y;
    }
    for (; p < e; ++p) {
        int j = __builtin_nontemporal_load(&col[p]);
        float2 f = __half22float2(mp[(size_t)j * 8 + fl]);
        ax += f.x; ay += f.y;
    }
    float2 fi = __half22float2(mp[(size_t)n * 8 + fl]);
    ax += fi.x; ay += fi.y;
    float di = dinv[n];
    float ox = fmaxf(fmaf(di, (ax + bx) + (cx + dx), b2.x), 0.f);
    float oy = fmaxf(fmaf(di, (ay + by) + (cy + dy), b2.y), 0.f);
    __half2 ho = __floats2half2_rn(ox, oy);
    unsigned int u = *reinterpret_cast<unsigned int*>(&ho);
    __builtin_nontemporal_store(
        u, reinterpret_cast<unsigned int*>(outp + slice * SL) + (size_t)n * 8 + fl);
}

// ---------------- Final aggregation + log_softmax (row-major 40) ---------
__global__ __launch_bounds__(256) void agg_out_kernel(
        const __half* __restrict__ m, const int* __restrict__ col,
        const int* __restrict__ start,
        const float* __restrict__ dinv, const float* __restrict__ bias,
        float* __restrict__ out, int N) {
    int w = (int)((blockIdx.x * 256 + threadIdx.x) >> 6);
    int lane = threadIdx.x & 63;
    if (w >= N) return;
    bool act = lane < NCLASS;
    int cl = act ? lane : 0;
    int s = start[w];
    int e = start[w + 1];
    float a0 = 0.f, a1 = 0.f;
    int p = s;
    for (; p + 8 <= e; p += 8) {
        int j[8];
#pragma unroll
        for (int u = 0; u < 8; ++u) j[u] = col[p + u];
        __half v[8];
#pragma unroll
        for (int u = 0; u < 8; ++u) v[u] = m[(size_t)j[u] * NCLASS + cl];
#pragma unroll
        for (int u = 0; u < 8; ++u) {
            if (u & 1) a1 += __half2float(v[u]);
            else       a0 += __half2float(v[u]);
        }
    }
    for (; p < e; ++p) a0 += __half2float(m[(size_t)col[p] * NCLASS + cl]);
    a0 += __half2float(m[(size_t)w * NCLASS + cl]);
    float di = dinv[w];
    float h = fmaxf(fmaf(di, a0 + a1, bias[cl]), 0.f);
    float hm = act ? h : -INFINITY;
#pragma unroll
    for (int off = 32; off; off >>= 1) hm = fmaxf(hm, __shfl_xor(hm, off, 64));
    float ex = act ? expf(h - hm) : 0.f;
    float se = ex;
#pragma unroll
    for (int off = 32; off; off >>= 1) se += __shfl_xor(se, off, 64);
    if (act) out[(size_t)w * NCLASS + lane] = h - hm - logf(se);
}

// ------------------------------ launch -----------------------------------

extern "C" void kernel_launch(void* const* d_in, const int* in_sizes, int n_in,
                              void* d_out, int out_size, void* d_ws, size_t ws_size,
                              hipStream_t stream) {
    const float* x  = (const float*)d_in[0];
    const int*   ei = (const int*)d_in[1];
    const float* W0 = (const float*)d_in[2];
    const float* b0 = (const float*)d_in[3];
    const float* W1 = (const float*)d_in[4];
    const float* b1 = (const float*)d_in[5];
    const float* W2 = (const float*)d_in[6];
    const float* b2 = (const float*)d_in[7];
    float* out = (float*)d_out;

    const int NFEATr = 256;
    const int N = in_sizes[0] / NFEATr;  // 100000
    const int E = in_sizes[1] / 2;       // 1600000
    const int* src = ei;
    const int* dst = ei + E;

    const int nbuk = (N + 63) >> 6;      // 1563
    const int chunk = (E + NBLK - 1) / NBLK;

    char* p = (char*)d_ws;
    auto alloc = [&](size_t bytes) -> void* {
        void* r = (void*)p;
        p += (bytes + 255) & ~(size_t)255;
        return r;
    };
    int*    bh     = (int*)alloc((size_t)NBLK * nbuk * 4);
    int*    T      = (int*)alloc((size_t)nbuk * 4);
    int*    BB     = (int*)alloc((size_t)(nbuk + 1) * 4);
    int*    offb   = (int*)alloc((size_t)NBLK * nbuk * 4);
    int*    eb     = (int*)alloc((size_t)E * 4);
    int*    col    = (int*)alloc((size_t)E * 4);
    int*    startA = (int*)alloc((size_t)(N + 1) * 4);
    float*  dinv   = (float*)alloc((size_t)N * 4);
    f16*    mbuf   = (f16*)alloc((size_t)N * NHID * 2);  // slice-major messages
    f16*    hbuf   = (f16*)alloc((size_t)N * NHID * 2);  // slice-major h
    f16*    m2buf  = (f16*)alloc((size_t)N * NCLASS * 2); // row-major 40-wide

    int nbl7 = (nbuk + 255) / 256;

    bucket_hist<<<NBLK, 256, 0, stream>>>(dst, bh, E, nbuk, chunk);
    bucket_total<<<nbl7, 256, 0, stream>>>(bh, T, nbuk);
    bucket_scan<<<1, 256, 0, stream>>>(T, BB, nbuk, E);
    bucket_expand<<<nbl7, 256, 0, stream>>>(bh, BB, offb, nbuk);
    bucket_scatter<<<NBLK, 256, 0, stream>>>(src, dst, offb, eb, E, nbuk, chunk);
    bucket_csr<<<nbuk, 256, 0, stream>>>(eb, BB, startA, dinv, col, N, E);

    int g128 = (N + 127) / 128;
    int g256 = (N + 255) / 256;
    int gagg = ((N + 31) / 32) * 8;   // 8 XCD-pinned slices
    int abl = (N + 3) / 4;

    // layer 0: x fp32 row-major @ W0 -> mbuf slice-major (prescaled)
    gemm_mfma<256, 128, 128, 2, 2, false, false, true><<<g128, 256, 0, stream>>>(
        (const void*)x, W0, dinv, mbuf, N, NHID);
    agg_slice<<<gagg, 256, 0, stream>>>(mbuf, col, startA, dinv, b0, hbuf, N);

    // layer 1: hbuf slice-major @ W1 -> mbuf slice-major (prescaled)
    gemm_mfma<128, 128, 128, 2, 2, false, true, true><<<g128, 256, 0, stream>>>(
        (const void*)hbuf, W1, dinv, mbuf, N, NHID);
    agg_slice<<<gagg, 256, 0, stream>>>(mbuf, col, startA, dinv, b1, hbuf, N);

    // layer 2: hbuf slice-major @ W2[128,40] -> m2buf row-major (prescaled)
    gemm_mfma<128, 256, 64, 4, 1, true, true, false><<<g256, 256, 0, stream>>>(
        (const void*)hbuf, W2, dinv, m2buf, N, NCLASS);
    agg_out_kernel<<<abl, 256, 0, stream>>>((const __half*)m2buf, col, startA, dinv, b2,
                                            out, N);
}

// Round 10
// 383.362 us; speedup vs baseline: 1.3318x; 1.3318x over previous
//
#include <hip/hip_runtime.h>
#include <hip/hip_bf16.h>
#include <hip/hip_fp16.h>
#include <math.h>

#define NHID 128
#define NCLASS 40
#define NBLK 256          // edge-chunk blocks for bucket passes
#define MAXBUK 1600       // >= ceil(N/64)

typedef _Float16 f16;
typedef f16 f16x8 __attribute__((ext_vector_type(8)));
typedef f16 f16x4 __attribute__((ext_vector_type(4)));
typedef float f32x4 __attribute__((ext_vector_type(4)));

// ---------------- CSR build: 2-level counting sort (LDS atomics only) ----
// eb entries packed: (src << 6) | (dst & 63)

__global__ __launch_bounds__(256) void bucket_hist(const int* __restrict__ dst,
                                                   int* __restrict__ bh,
                                                   int E, int nbuk, int chunk) {
    __shared__ int h[MAXBUK];
    for (int i = threadIdx.x; i < nbuk; i += 256) h[i] = 0;
    __syncthreads();
    int b = blockIdx.x;
    int lo = b * chunk, hi = min(E, lo + chunk);
    for (int e = lo + threadIdx.x; e < hi; e += 256) atomicAdd(&h[dst[e] >> 6], 1);
    __syncthreads();
    for (int i = threadIdx.x; i < nbuk; i += 256) bh[(size_t)b * nbuk + i] = h[i];
}

__global__ __launch_bounds__(256) void bucket_total(const int* __restrict__ bh,
                                                    int* __restrict__ T, int nbuk) {
    int buk = blockIdx.x * 256 + threadIdx.x;
    if (buk >= nbuk) return;
    int s = 0;
    for (int b = 0; b < NBLK; ++b) s += bh[(size_t)b * nbuk + buk];
    T[buk] = s;
}

__global__ __launch_bounds__(256) void bucket_scan(const int* __restrict__ T,
                                                   int* __restrict__ BB, int nbuk, int E) {
    __shared__ int sc[256];
    __shared__ int carry;
    if (threadIdx.x == 0) carry = 0;
    __syncthreads();
    for (int base = 0; base < nbuk; base += 256) {
        int i = base + threadIdx.x;
        int v = (i < nbuk) ? T[i] : 0;
        sc[threadIdx.x] = v;
        __syncthreads();
        for (int off = 1; off < 256; off <<= 1) {
            int t = (threadIdx.x >= off) ? sc[threadIdx.x - off] : 0;
            __syncthreads();
            sc[threadIdx.x] += t;
            __syncthreads();
        }
        if (i < nbuk) BB[i] = carry + sc[threadIdx.x] - v;
        __syncthreads();
        if (threadIdx.x == 255) carry += sc[255];
        __syncthreads();
    }
    if (threadIdx.x == 0) BB[nbuk] = E;
}

__global__ __launch_bounds__(256) void bucket_expand(const int* __restrict__ bh,
                                                     const int* __restrict__ BB,
                                                     int* __restrict__ off, int nbuk) {
    int buk = blockIdx.x * 256 + threadIdx.x;
    if (buk >= nbuk) return;
    int run = BB[buk];
    for (int b = 0; b < NBLK; ++b) {
        off[(size_t)b * nbuk + buk] = run;
        run += bh[(size_t)b * nbuk + buk];
    }
}

__global__ __launch_bounds__(256) void bucket_scatter(const int* __restrict__ src,
                                                      const int* __restrict__ dst,
                                                      const int* __restrict__ off,
                                                      int* __restrict__ eb,
                                                      int E, int nbuk, int chunk) {
    __shared__ int cur[MAXBUK];
    int b = blockIdx.x;
    for (int i = threadIdx.x; i < nbuk; i += 256) cur[i] = off[(size_t)b * nbuk + i];
    __syncthreads();
    int lo = b * chunk, hi = min(E, lo + chunk);
    for (int e = lo + threadIdx.x; e < hi; e += 256) {
        int d = dst[e], s = src[e];
        int pos = atomicAdd(&cur[d >> 6], 1);
        eb[pos] = (s << 6) | (d & 63);
    }
}

__global__ __launch_bounds__(256) void bucket_csr(const int* __restrict__ eb,
                                                  const int* __restrict__ BB,
                                                  int* __restrict__ startA,
                                                  float* __restrict__ dinv,
                                                  int* __restrict__ col,
                                                  int N, int E) {
    __shared__ int h[64];
    int b = blockIdx.x;
    int bs = BB[b], be = BB[b + 1];
    if (threadIdx.x < 64) h[threadIdx.x] = 0;
    __syncthreads();
    for (int i = bs + threadIdx.x; i < be; i += 256) atomicAdd(&h[eb[i] & 63], 1);
    __syncthreads();
    if (threadIdx.x < 64) {  // wave 0
        int v = h[threadIdx.x];
        int incl = v;
#pragma unroll
        for (int o = 1; o < 64; o <<= 1) {
            int t = __shfl_up(incl, o, 64);
            if ((int)threadIdx.x >= o) incl += t;
        }
        int n = (b << 6) + threadIdx.x;
        if (n < N) {
            startA[n] = bs + incl - v;
            dinv[n] = rsqrtf((float)(v + 1));  // +1 self-loop
        }
        h[threadIdx.x] = incl - v;  // reuse as cursor
    }
    __syncthreads();
    for (int i = bs + threadIdx.x; i < be; i += 256) {
        int pk = eb[i];
        int pos = bs + atomicAdd(&h[pk & 63], 1);
        col[pos] = pk >> 6;
    }
    if (b == 0 && threadIdx.x == 0) startA[N] = E;
}

// --------------------------- MFMA GEMM (R3-proven) -----------------------
// C = dinv[row] * (A @ W), fp16 out, row-major.
template <int K, int BM, int BN, int WM, int WN, bool GUARDN, bool AHALF>
__global__ __launch_bounds__(256) void gemm_mfma(const void* __restrict__ Ap,
                                                 const float* __restrict__ W,
                                                 const float* __restrict__ dinv,
                                                 f16* __restrict__ C, int M, int N) {
    constexpr int KC = 64;
    __shared__ f16 As[BM * KC];
    __shared__ f16 Bs[BN * KC];
    __shared__ float sdinv[BM];
    const int t = threadIdx.x;
    const int wid = t >> 6, lane = t & 63;
    const int wm = wid % WM, wn = wid / WM;
    const int row0 = blockIdx.x * BM;

    for (int i = t; i < BM; i += 256) {
        int r = row0 + i;
        sdinv[i] = dinv[r < M ? r : M - 1];
    }

    f32x4 acc[4][4] = {};

    for (int k0 = 0; k0 < K; k0 += KC) {
        if (AHALF) {
            const f16* A = (const f16*)Ap;
#pragma unroll
            for (int i = 0; i < BM / 32; ++i) {
                int g = t + i * 256;
                int r = g >> 3, c = g & 7;
                int grow = row0 + r; if (grow >= M) grow = M - 1;
                f16x8 v = *reinterpret_cast<const f16x8*>(&A[(size_t)grow * K + k0 + c * 8]);
                *reinterpret_cast<f16x8*>(&As[r * 64 + ((c ^ (r & 7)) << 3)]) = v;
            }
        } else {
            const float* A = (const float*)Ap;
#pragma unroll
            for (int i = 0; i < BM / 32; ++i) {
                int g = t + i * 256;
                int r = g >> 3, c = g & 7;
                int grow = row0 + r; if (grow >= M) grow = M - 1;
                const float* s = &A[(size_t)grow * K + k0 + c * 8];
                float4 a = *reinterpret_cast<const float4*>(s);
                float4 b = *reinterpret_cast<const float4*>(s + 4);
                f16x8 v = {(f16)a.x, (f16)a.y, (f16)a.z, (f16)a.w,
                           (f16)b.x, (f16)b.y, (f16)b.z, (f16)b.w};
                *reinterpret_cast<f16x8*>(&As[r * 64 + ((c ^ (r & 7)) << 3)]) = v;
            }
        }
        if (!GUARDN) {
#pragma unroll
            for (int i = 0; i < BN / 16; ++i) {
                int v = t + i * 256;
                int kk = v / (BN / 4), nq = v % (BN / 4);
                float4 w = *reinterpret_cast<const float4*>(&W[(size_t)(k0 + kk) * N + nq * 4]);
                float ws[4] = {w.x, w.y, w.z, w.w};
#pragma unroll
                for (int j = 0; j < 4; ++j) {
                    int n = nq * 4 + j;
                    Bs[n * 64 + (((kk >> 3) ^ (n & 7)) << 3) + (kk & 7)] = (f16)ws[j];
                }
            }
        } else {
#pragma unroll
            for (int i = 0; i < BN / 16; ++i) {
                int v = t + i * 256;
                int kk = v / (BN / 4), nq = v % (BN / 4);
#pragma unroll
                for (int j = 0; j < 4; ++j) {
                    int n = nq * 4 + j;
                    float wv = (n < N) ? W[(size_t)(k0 + kk) * N + n] : 0.f;
                    Bs[n * 64 + (((kk >> 3) ^ (n & 7)) << 3) + (kk & 7)] = (f16)wv;
                }
            }
        }
        __syncthreads();

#pragma unroll
        for (int s = 0; s < 2; ++s) {
            f16x8 af[4], bf[4];
            int c = s * 4 + (lane >> 4);
#pragma unroll
            for (int mf = 0; mf < 4; ++mf) {
                int r = wm * 64 + mf * 16 + (lane & 15);
                af[mf] = *reinterpret_cast<const f16x8*>(&As[r * 64 + ((c ^ (r & 7)) << 3)]);
            }
#pragma unroll
            for (int nf = 0; nf < 4; ++nf) {
                int n = wn * 64 + nf * 16 + (lane & 15);
                bf[nf] = *reinterpret_cast<const f16x8*>(&Bs[n * 64 + ((c ^ (n & 7)) << 3)]);
            }
#pragma unroll
            for (int mf = 0; mf < 4; ++mf)
#pragma unroll
                for (int nf = 0; nf < 4; ++nf)
                    acc[mf][nf] = __builtin_amdgcn_mfma_f32_16x16x32_f16(af[mf], bf[nf],
                                                                         acc[mf][nf], 0, 0, 0);
        }
        __syncthreads();
    }

#pragma unroll
    for (int mf = 0; mf < 4; ++mf) {
#pragma unroll
        for (int q = 0; q < 4; ++q) {
            int lr = wm * 64 + mf * 16 + (lane >> 4) * 4 + q;
            int grow = row0 + lr;
            if (grow < M) {
                float scl = sdinv[lr];
#pragma unroll
                for (int nf = 0; nf < 4; ++nf) {
                    int gcol = wn * 64 + nf * 16 + (lane & 15);
                    if (!GUARDN || gcol < N)
                        C[(size_t)grow * N + gcol] = (f16)(acc[mf][nf][q] * scl);
                }
            }
        }
    }
}

// --------------------------- Aggregation --------------------------------
// One wave per node, 4 EDGES PER GATHER INSTRUCTION: lane = (eg = lane>>4,
// fl = lane&15). Each lane loads 16B (f16x8) of edge (p+eg)'s 256B row ->
// one instruction covers 4 full rows. Edge-group partials combined with
// 2 shfl_xor rounds per node. Messages pre-scaled by dinv[src].
__global__ __launch_bounds__(256) void agg_h_kernel(
        const f16* __restrict__ m, const int* __restrict__ col,
        const int* __restrict__ start, const float* __restrict__ dinv,
        const float* __restrict__ bias, f16* __restrict__ out, int N) {
    int w = (int)((blockIdx.x * 256 + threadIdx.x) >> 6);
    int lane = threadIdx.x & 63;
    if (w >= N) return;
    const int eg = lane >> 4, fl = lane & 15;
    int s = start[w], e = start[w + 1];
    float a[8] = {};
    int full = s + ((e - s) & ~3);
    for (int p = s; p < full; p += 4) {
        int j = col[p + eg];
        f16x8 v = *reinterpret_cast<const f16x8*>(&m[(size_t)j * 128 + fl * 8]);
#pragma unroll
        for (int u = 0; u < 8; ++u) a[u] += (float)v[u];
    }
    if (full < e) {
        int idx = full + eg;
        bool val = idx < e;
        int j = col[val ? idx : s];
        f16x8 v = *reinterpret_cast<const f16x8*>(&m[(size_t)j * 128 + fl * 8]);
        if (val) {
#pragma unroll
            for (int u = 0; u < 8; ++u) a[u] += (float)v[u];
        }
    }
    if (eg == 0) {  // self-loop once
        f16x8 v = *reinterpret_cast<const f16x8*>(&m[(size_t)w * 128 + fl * 8]);
#pragma unroll
        for (int u = 0; u < 8; ++u) a[u] += (float)v[u];
    }
#pragma unroll
    for (int off = 16; off <= 32; off <<= 1)
#pragma unroll
        for (int u = 0; u < 8; ++u) a[u] += __shfl_xor(a[u], off, 64);
    if (eg == 0) {
        float di = dinv[w];
        float4 bA = *reinterpret_cast<const float4*>(&bias[fl * 8]);
        float4 bB = *reinterpret_cast<const float4*>(&bias[fl * 8 + 4]);
        float bb[8] = {bA.x, bA.y, bA.z, bA.w, bB.x, bB.y, bB.z, bB.w};
        f16x8 o;
#pragma unroll
        for (int u = 0; u < 8; ++u) o[u] = (f16)fmaxf(fmaf(di, a[u], bb[u]), 0.f);
        *reinterpret_cast<f16x8*>(&out[(size_t)w * 128 + fl * 8]) = o;
    }
}

// Final layer: 40-wide rows (80B). Same 4-edges/instruction scheme with
// fl<10 active (half4 per lane), then log_softmax via intra-group shuffles.
__global__ __launch_bounds__(256) void agg_out_kernel(
        const f16* __restrict__ m, const int* __restrict__ col,
        const int* __restrict__ start, const float* __restrict__ dinv,
        const float* __restrict__ bias, float* __restrict__ out, int N) {
    int w = (int)((blockIdx.x * 256 + threadIdx.x) >> 6);
    int lane = threadIdx.x & 63;
    if (w >= N) return;
    const int eg = lane >> 4, fl = lane & 15;
    const bool act = fl < 10;
    const int base = fl * 4;
    int s = start[w], e = start[w + 1];
    float a[4] = {};
    int full = s + ((e - s) & ~3);
    for (int p = s; p < full; p += 4) {
        int j = col[p + eg];
        if (act) {
            f16x4 v = *reinterpret_cast<const f16x4*>(&m[(size_t)j * NCLASS + base]);
#pragma unroll
            for (int u = 0; u < 4; ++u) a[u] += (float)v[u];
        }
    }
    if (full < e) {
        int idx = full + eg;
        bool val = idx < e;
        int j = col[val ? idx : s];
        if (act) {
            f16x4 v = *reinterpret_cast<const f16x4*>(&m[(size_t)j * NCLASS + base]);
            if (val) {
#pragma unroll
                for (int u = 0; u < 4; ++u) a[u] += (float)v[u];
            }
        }
    }
    if (eg == 0 && act) {
        f16x4 v = *reinterpret_cast<const f16x4*>(&m[(size_t)w * NCLASS + base]);
#pragma unroll
        for (int u = 0; u < 4; ++u) a[u] += (float)v[u];
    }
#pragma unroll
    for (int off = 16; off <= 32; off <<= 1)
#pragma unroll
        for (int u = 0; u < 4; ++u) a[u] += __shfl_xor(a[u], off, 64);
    // bias + relu
    float di = dinv[w];
    float h[4];
    float mx = -INFINITY;
#pragma unroll
    for (int u = 0; u < 4; ++u) {
        h[u] = act ? fmaxf(fmaf(di, a[u], bias[base + u]), 0.f) : -INFINITY;
        mx = fmaxf(mx, h[u]);
    }
#pragma unroll
    for (int off = 1; off <= 8; off <<= 1) mx = fmaxf(mx, __shfl_xor(mx, off, 64));
    float se = 0.f;
#pragma unroll
    for (int u = 0; u < 4; ++u) se += act ? expf(h[u] - mx) : 0.f;
#pragma unroll
    for (int off = 1; off <= 8; off <<= 1) se += __shfl_xor(se, off, 64);
    if (eg == 0 && act) {
        float ls = logf(se);
        float4 o = make_float4(h[0] - mx - ls, h[1] - mx - ls,
                               h[2] - mx - ls, h[3] - mx - ls);
        *reinterpret_cast<float4*>(&out[(size_t)w * NCLASS + base]) = o;
    }
}

// ------------------------------ launch -----------------------------------

extern "C" void kernel_launch(void* const* d_in, const int* in_sizes, int n_in,
                              void* d_out, int out_size, void* d_ws, size_t ws_size,
                              hipStream_t stream) {
    const float* x  = (const float*)d_in[0];
    const int*   ei = (const int*)d_in[1];
    const float* W0 = (const float*)d_in[2];
    const float* b0 = (const float*)d_in[3];
    const float* W1 = (const float*)d_in[4];
    const float* b1 = (const float*)d_in[5];
    const float* W2 = (const float*)d_in[6];
    const float* b2 = (const float*)d_in[7];
    float* out = (float*)d_out;

    const int NFEATr = 256;
    const int N = in_sizes[0] / NFEATr;  // 100000
    const int E = in_sizes[1] / 2;       // 1600000
    const int* src = ei;
    const int* dst = ei + E;

    const int nbuk = (N + 63) >> 6;      // 1563
    const int chunk = (E + NBLK - 1) / NBLK;

    char* p = (char*)d_ws;
    auto alloc = [&](size_t bytes) -> void* {
        void* r = (void*)p;
        p += (bytes + 255) & ~(size_t)255;
        return r;
    };
    int*    bh     = (int*)alloc((size_t)NBLK * nbuk * 4);
    int*    T      = (int*)alloc((size_t)nbuk * 4);
    int*    BB     = (int*)alloc((size_t)(nbuk + 1) * 4);
    int*    offb   = (int*)alloc((size_t)NBLK * nbuk * 4);
    int*    eb     = (int*)alloc((size_t)E * 4);
    int*    col    = (int*)alloc((size_t)E * 4);
    int*    startA = (int*)alloc((size_t)(N + 1) * 4);
    float*  dinv   = (float*)alloc((size_t)N * 4);
    f16*    mbuf   = (f16*)alloc((size_t)N * NHID * 2);
    f16*    hbuf   = (f16*)alloc((size_t)N * NHID * 2);

    int nbl7 = (nbuk + 255) / 256;

    bucket_hist<<<NBLK, 256, 0, stream>>>(dst, bh, E, nbuk, chunk);
    bucket_total<<<nbl7, 256, 0, stream>>>(bh, T, nbuk);
    bucket_scan<<<1, 256, 0, stream>>>(T, BB, nbuk, E);
    bucket_expand<<<nbl7, 256, 0, stream>>>(bh, BB, offb, nbuk);
    bucket_scatter<<<NBLK, 256, 0, stream>>>(src, dst, offb, eb, E, nbuk, chunk);
    bucket_csr<<<nbuk, 256, 0, stream>>>(eb, BB, startA, dinv, col, N, E);

    int abl = (N + 3) / 4;
    int g128 = (N + 127) / 128;
    int g256 = (N + 255) / 256;

    // layer 0: x fp32 [N,256] @ W0 -> mbuf f16 (prescaled by dinv[row])
    gemm_mfma<256, 128, 128, 2, 2, false, false><<<g128, 256, 0, stream>>>(
        (const void*)x, W0, dinv, mbuf, N, NHID);
    agg_h_kernel<<<abl, 256, 0, stream>>>(mbuf, col, startA, dinv, b0, hbuf, N);

    // layer 1
    gemm_mfma<128, 128, 128, 2, 2, false, true><<<g128, 256, 0, stream>>>(
        (const void*)hbuf, W1, dinv, mbuf, N, NHID);
    agg_h_kernel<<<abl, 256, 0, stream>>>(mbuf, col, startA, dinv, b1, hbuf, N);

    // layer 2 (40-wide messages)
    gemm_mfma<128, 256, 64, 4, 1, true, true><<<g256, 256, 0, stream>>>(
        (const void*)hbuf, W2, dinv, mbuf, N, NCLASS);
    agg_out_kernel<<<abl, 256, 0, stream>>>(mbuf, col, startA, dinv, b2, out, N);
}

// Round 11
// 373.330 us; speedup vs baseline: 1.3676x; 1.0269x over previous
//
#include <hip/hip_runtime.h>
#include <hip/hip_bf16.h>
#include <hip/hip_fp16.h>
#include <math.h>

#define NHID 128
#define NCLASS 40
#define NBLK 256          // edge-chunk blocks for bucket passes
#define MAXBUK 1600       // >= ceil(N/64)

typedef _Float16 f16;
typedef f16 f16x8 __attribute__((ext_vector_type(8)));
typedef float f32x4 __attribute__((ext_vector_type(4)));

// ---------------- CSR build: 2-level counting sort (LDS atomics only) ----
// eb entries packed: (src << 6) | (dst & 63)

__global__ __launch_bounds__(256) void bucket_hist(const int* __restrict__ dst,
                                                   int* __restrict__ bh,
                                                   int E, int nbuk, int chunk) {
    __shared__ int h[MAXBUK];
    for (int i = threadIdx.x; i < nbuk; i += 256) h[i] = 0;
    __syncthreads();
    int b = blockIdx.x;
    int lo = b * chunk, hi = min(E, lo + chunk);
    for (int e = lo + threadIdx.x; e < hi; e += 256) atomicAdd(&h[dst[e] >> 6], 1);
    __syncthreads();
    for (int i = threadIdx.x; i < nbuk; i += 256) bh[(size_t)b * nbuk + i] = h[i];
}

__global__ __launch_bounds__(256) void bucket_total(const int* __restrict__ bh,
                                                    int* __restrict__ T, int nbuk) {
    int buk = blockIdx.x * 256 + threadIdx.x;
    if (buk >= nbuk) return;
    int s = 0;
    for (int b = 0; b < NBLK; ++b) s += bh[(size_t)b * nbuk + buk];
    T[buk] = s;
}

__global__ __launch_bounds__(256) void bucket_scan(const int* __restrict__ T,
                                                   int* __restrict__ BB, int nbuk, int E) {
    __shared__ int sc[256];
    __shared__ int carry;
    if (threadIdx.x == 0) carry = 0;
    __syncthreads();
    for (int base = 0; base < nbuk; base += 256) {
        int i = base + threadIdx.x;
        int v = (i < nbuk) ? T[i] : 0;
        sc[threadIdx.x] = v;
        __syncthreads();
        for (int off = 1; off < 256; off <<= 1) {
            int t = (threadIdx.x >= off) ? sc[threadIdx.x - off] : 0;
            __syncthreads();
            sc[threadIdx.x] += t;
            __syncthreads();
        }
        if (i < nbuk) BB[i] = carry + sc[threadIdx.x] - v;
        __syncthreads();
        if (threadIdx.x == 255) carry += sc[255];
        __syncthreads();
    }
    if (threadIdx.x == 0) BB[nbuk] = E;
}

__global__ __launch_bounds__(256) void bucket_expand(const int* __restrict__ bh,
                                                     const int* __restrict__ BB,
                                                     int* __restrict__ off, int nbuk) {
    int buk = blockIdx.x * 256 + threadIdx.x;
    if (buk >= nbuk) return;
    int run = BB[buk];
    for (int b = 0; b < NBLK; ++b) {
        off[(size_t)b * nbuk + buk] = run;
        run += bh[(size_t)b * nbuk + buk];
    }
}

__global__ __launch_bounds__(256) void bucket_scatter(const int* __restrict__ src,
                                                      const int* __restrict__ dst,
                                                      const int* __restrict__ off,
                                                      int* __restrict__ eb,
                                                      int E, int nbuk, int chunk) {
    __shared__ int cur[MAXBUK];
    int b = blockIdx.x;
    for (int i = threadIdx.x; i < nbuk; i += 256) cur[i] = off[(size_t)b * nbuk + i];
    __syncthreads();
    int lo = b * chunk, hi = min(E, lo + chunk);
    for (int e = lo + threadIdx.x; e < hi; e += 256) {
        int d = dst[e], s = src[e];
        int pos = atomicAdd(&cur[d >> 6], 1);
        eb[pos] = (s << 6) | (d & 63);
    }
}

__global__ __launch_bounds__(256) void bucket_csr(const int* __restrict__ eb,
                                                  const int* __restrict__ BB,
                                                  int* __restrict__ startA,
                                                  float* __restrict__ dinv,
                                                  int* __restrict__ col,
                                                  int N, int E) {
    __shared__ int h[64];
    int b = blockIdx.x;
    int bs = BB[b], be = BB[b + 1];
    if (threadIdx.x < 64) h[threadIdx.x] = 0;
    __syncthreads();
    for (int i = bs + threadIdx.x; i < be; i += 256) atomicAdd(&h[eb[i] & 63], 1);
    __syncthreads();
    if (threadIdx.x < 64) {  // wave 0
        int v = h[threadIdx.x];
        int incl = v;
#pragma unroll
        for (int o = 1; o < 64; o <<= 1) {
            int t = __shfl_up(incl, o, 64);
            if ((int)threadIdx.x >= o) incl += t;
        }
        int n = (b << 6) + threadIdx.x;
        if (n < N) {
            startA[n] = bs + incl - v;
            dinv[n] = rsqrtf((float)(v + 1));  // +1 self-loop
        }
        h[threadIdx.x] = incl - v;  // reuse as cursor
    }
    __syncthreads();
    for (int i = bs + threadIdx.x; i < be; i += 256) {
        int pk = eb[i];
        int pos = bs + atomicAdd(&h[pk & 63], 1);
        col[pos] = pk >> 6;
    }
    if (b == 0 && threadIdx.x == 0) startA[N] = E;
}

// --------------------------- MFMA GEMM (R3-proven) -----------------------
// C = dinv[row] * (A @ W), fp16 out, row-major.
template <int K, int BM, int BN, int WM, int WN, bool GUARDN, bool AHALF>
__global__ __launch_bounds__(256) void gemm_mfma(const void* __restrict__ Ap,
                                                 const float* __restrict__ W,
                                                 const float* __restrict__ dinv,
                                                 f16* __restrict__ C, int M, int N) {
    constexpr int KC = 64;
    __shared__ f16 As[BM * KC];
    __shared__ f16 Bs[BN * KC];
    __shared__ float sdinv[BM];
    const int t = threadIdx.x;
    const int wid = t >> 6, lane = t & 63;
    const int wm = wid % WM, wn = wid / WM;
    const int row0 = blockIdx.x * BM;

    for (int i = t; i < BM; i += 256) {
        int r = row0 + i;
        sdinv[i] = dinv[r < M ? r : M - 1];
    }

    f32x4 acc[4][4] = {};

    for (int k0 = 0; k0 < K; k0 += KC) {
        if (AHALF) {
            const f16* A = (const f16*)Ap;
#pragma unroll
            for (int i = 0; i < BM / 32; ++i) {
                int g = t + i * 256;
                int r = g >> 3, c = g & 7;
                int grow = row0 + r; if (grow >= M) grow = M - 1;
                f16x8 v = *reinterpret_cast<const f16x8*>(&A[(size_t)grow * K + k0 + c * 8]);
                *reinterpret_cast<f16x8*>(&As[r * 64 + ((c ^ (r & 7)) << 3)]) = v;
            }
        } else {
            const float* A = (const float*)Ap;
#pragma unroll
            for (int i = 0; i < BM / 32; ++i) {
                int g = t + i * 256;
                int r = g >> 3, c = g & 7;
                int grow = row0 + r; if (grow >= M) grow = M - 1;
                const float* s = &A[(size_t)grow * K + k0 + c * 8];
                float4 a = *reinterpret_cast<const float4*>(s);
                float4 b = *reinterpret_cast<const float4*>(s + 4);
                f16x8 v = {(f16)a.x, (f16)a.y, (f16)a.z, (f16)a.w,
                           (f16)b.x, (f16)b.y, (f16)b.z, (f16)b.w};
                *reinterpret_cast<f16x8*>(&As[r * 64 + ((c ^ (r & 7)) << 3)]) = v;
            }
        }
        if (!GUARDN) {
#pragma unroll
            for (int i = 0; i < BN / 16; ++i) {
                int v = t + i * 256;
                int kk = v / (BN / 4), nq = v % (BN / 4);
                float4 w = *reinterpret_cast<const float4*>(&W[(size_t)(k0 + kk) * N + nq * 4]);
                float ws[4] = {w.x, w.y, w.z, w.w};
#pragma unroll
                for (int j = 0; j < 4; ++j) {
                    int n = nq * 4 + j;
                    Bs[n * 64 + (((kk >> 3) ^ (n & 7)) << 3) + (kk & 7)] = (f16)ws[j];
                }
            }
        } else {
#pragma unroll
            for (int i = 0; i < BN / 16; ++i) {
                int v = t + i * 256;
                int kk = v / (BN / 4), nq = v % (BN / 4);
#pragma unroll
                for (int j = 0; j < 4; ++j) {
                    int n = nq * 4 + j;
                    float wv = (n < N) ? W[(size_t)(k0 + kk) * N + n] : 0.f;
                    Bs[n * 64 + (((kk >> 3) ^ (n & 7)) << 3) + (kk & 7)] = (f16)wv;
                }
            }
        }
        __syncthreads();

#pragma unroll
        for (int s = 0; s < 2; ++s) {
            f16x8 af[4], bf[4];
            int c = s * 4 + (lane >> 4);
#pragma unroll
            for (int mf = 0; mf < 4; ++mf) {
                int r = wm * 64 + mf * 16 + (lane & 15);
                af[mf] = *reinterpret_cast<const f16x8*>(&As[r * 64 + ((c ^ (r & 7)) << 3)]);
            }
#pragma unroll
            for (int nf = 0; nf < 4; ++nf) {
                int n = wn * 64 + nf * 16 + (lane & 15);
                bf[nf] = *reinterpret_cast<const f16x8*>(&Bs[n * 64 + ((c ^ (n & 7)) << 3)]);
            }
#pragma unroll
            for (int mf = 0; mf < 4; ++mf)
#pragma unroll
                for (int nf = 0; nf < 4; ++nf)
                    acc[mf][nf] = __builtin_amdgcn_mfma_f32_16x16x32_f16(af[mf], bf[nf],
                                                                         acc[mf][nf], 0, 0, 0);
        }
        __syncthreads();
    }

#pragma unroll
    for (int mf = 0; mf < 4; ++mf) {
#pragma unroll
        for (int q = 0; q < 4; ++q) {
            int lr = wm * 64 + mf * 16 + (lane >> 4) * 4 + q;
            int grow = row0 + lr;
            if (grow < M) {
                float scl = sdinv[lr];
#pragma unroll
                for (int nf = 0; nf < 4; ++nf) {
                    int gcol = wn * 64 + nf * 16 + (lane & 15);
                    if (!GUARDN || gcol < N)
                        C[(size_t)grow * N + gcol] = (f16)(acc[mf][nf][q] * scl);
                }
            }
        }
    }
}

// --------------------------- Aggregation --------------------------------
// One wave per node, 4 EDGES PER GATHER INSTRUCTION: lane = (eg = lane>>4,
// fl = lane&15). Each lane loads 16B (f16x8) of edge (p+eg)'s 256B row ->
// one instruction covers 4 full rows. Edge-group partials combined with
// 2 shfl_xor rounds per node. Messages pre-scaled by dinv[src].
__global__ __launch_bounds__(256) void agg_h_kernel(
        const f16* __restrict__ m, const int* __restrict__ col,
        const int* __restrict__ start, const float* __restrict__ dinv,
        const float* __restrict__ bias, f16* __restrict__ out, int N) {
    int w = (int)((blockIdx.x * 256 + threadIdx.x) >> 6);
    int lane = threadIdx.x & 63;
    if (w >= N) return;
    const int eg = lane >> 4, fl = lane & 15;
    int s = start[w], e = start[w + 1];
    float a[8] = {};
    int full = s + ((e - s) & ~3);
    for (int p = s; p < full; p += 4) {
        int j = col[p + eg];
        f16x8 v = *reinterpret_cast<const f16x8*>(&m[(size_t)j * 128 + fl * 8]);
#pragma unroll
        for (int u = 0; u < 8; ++u) a[u] += (float)v[u];
    }
    if (full < e) {
        int idx = full + eg;
        bool val = idx < e;
        int j = col[val ? idx : s];
        f16x8 v = *reinterpret_cast<const f16x8*>(&m[(size_t)j * 128 + fl * 8]);
        if (val) {
#pragma unroll
            for (int u = 0; u < 8; ++u) a[u] += (float)v[u];
        }
    }
    if (eg == 0) {  // self-loop once
        f16x8 v = *reinterpret_cast<const f16x8*>(&m[(size_t)w * 128 + fl * 8]);
#pragma unroll
        for (int u = 0; u < 8; ++u) a[u] += (float)v[u];
    }
#pragma unroll
    for (int off = 16; off <= 32; off <<= 1)
#pragma unroll
        for (int u = 0; u < 8; ++u) a[u] += __shfl_xor(a[u], off, 64);
    if (eg == 0) {
        float di = dinv[w];
        float4 bA = *reinterpret_cast<const float4*>(&bias[fl * 8]);
        float4 bB = *reinterpret_cast<const float4*>(&bias[fl * 8 + 4]);
        float bb[8] = {bA.x, bA.y, bA.z, bA.w, bB.x, bB.y, bB.z, bB.w};
        f16x8 o;
#pragma unroll
        for (int u = 0; u < 8; ++u) o[u] = (f16)fmaxf(fmaf(di, a[u], bb[u]), 0.f);
        *reinterpret_cast<f16x8*>(&out[(size_t)w * 128 + fl * 8]) = o;
    }
}

// Final layer (R3-proven): lane = class, one 80B row per instruction,
// 8-deep pipeline, wave-wide log_softmax.
__global__ __launch_bounds__(256) void agg_out_kernel(
        const __half* __restrict__ m, const int* __restrict__ col,
        const int* __restrict__ start,
        const float* __restrict__ dinv, const float* __restrict__ bias,
        float* __restrict__ out, int N) {
    int w = (int)((blockIdx.x * 256 + threadIdx.x) >> 6);
    int lane = threadIdx.x & 63;
    if (w >= N) return;
    bool act = lane < NCLASS;
    int cl = act ? lane : 0;
    int s = start[w];
    int e = start[w + 1];
    float a0 = 0.f, a1 = 0.f;
    int p = s;
    for (; p + 8 <= e; p += 8) {
        int j[8];
#pragma unroll
        for (int u = 0; u < 8; ++u) j[u] = col[p + u];
        __half v[8];
#pragma unroll
        for (int u = 0; u < 8; ++u) v[u] = m[(size_t)j[u] * NCLASS + cl];
#pragma unroll
        for (int u = 0; u < 8; ++u) {
            if (u & 1) a1 += __half2float(v[u]);
            else       a0 += __half2float(v[u]);
        }
    }
    for (; p < e; ++p) a0 += __half2float(m[(size_t)col[p] * NCLASS + cl]);
    a0 += __half2float(m[(size_t)w * NCLASS + cl]);
    float di = dinv[w];
    float h = fmaxf(fmaf(di, a0 + a1, bias[cl]), 0.f);
    float hm = act ? h : -INFINITY;
#pragma unroll
    for (int off = 32; off; off >>= 1) hm = fmaxf(hm, __shfl_xor(hm, off, 64));
    float ex = act ? expf(h - hm) : 0.f;
    float se = ex;
#pragma unroll
    for (int off = 32; off; off >>= 1) se += __shfl_xor(se, off, 64);
    if (act) out[(size_t)w * NCLASS + lane] = h - hm - logf(se);
}

// ------------------------------ launch -----------------------------------

extern "C" void kernel_launch(void* const* d_in, const int* in_sizes, int n_in,
                              void* d_out, int out_size, void* d_ws, size_t ws_size,
                              hipStream_t stream) {
    const float* x  = (const float*)d_in[0];
    const int*   ei = (const int*)d_in[1];
    const float* W0 = (const float*)d_in[2];
    const float* b0 = (const float*)d_in[3];
    const float* W1 = (const float*)d_in[4];
    const float* b1 = (const float*)d_in[5];
    const float* W2 = (const float*)d_in[6];
    const float* b2 = (const float*)d_in[7];
    float* out = (float*)d_out;

    const int NFEATr = 256;
    const int N = in_sizes[0] / NFEATr;  // 100000
    const int E = in_sizes[1] / 2;       // 1600000
    const int* src = ei;
    const int* dst = ei + E;

    const int nbuk = (N + 63) >> 6;      // 1563
    const int chunk = (E + NBLK - 1) / NBLK;

    char* p = (char*)d_ws;
    auto alloc = [&](size_t bytes) -> void* {
        void* r = (void*)p;
        p += (bytes + 255) & ~(size_t)255;
        return r;
    };
    int*    bh     = (int*)alloc((size_t)NBLK * nbuk * 4);
    int*    T      = (int*)alloc((size_t)nbuk * 4);
    int*    BB     = (int*)alloc((size_t)(nbuk + 1) * 4);
    int*    offb   = (int*)alloc((size_t)NBLK * nbuk * 4);
    int*    eb     = (int*)alloc((size_t)E * 4);
    int*    col    = (int*)alloc((size_t)E * 4);
    int*    startA = (int*)alloc((size_t)(N + 1) * 4);
    float*  dinv   = (float*)alloc((size_t)N * 4);
    f16*    mbuf   = (f16*)alloc((size_t)N * NHID * 2);
    f16*    hbuf   = (f16*)alloc((size_t)N * NHID * 2);

    int nbl7 = (nbuk + 255) / 256;

    bucket_hist<<<NBLK, 256, 0, stream>>>(dst, bh, E, nbuk, chunk);
    bucket_total<<<nbl7, 256, 0, stream>>>(bh, T, nbuk);
    bucket_scan<<<1, 256, 0, stream>>>(T, BB, nbuk, E);
    bucket_expand<<<nbl7, 256, 0, stream>>>(bh, BB, offb, nbuk);
    bucket_scatter<<<NBLK, 256, 0, stream>>>(src, dst, offb, eb, E, nbuk, chunk);
    bucket_csr<<<nbuk, 256, 0, stream>>>(eb, BB, startA, dinv, col, N, E);

    int abl = (N + 3) / 4;
    int g128 = (N + 127) / 128;
    int g256 = (N + 255) / 256;

    // layer 0: x fp32 [N,256] @ W0 -> mbuf f16 (prescaled by dinv[row])
    gemm_mfma<256, 128, 128, 2, 2, false, false><<<g128, 256, 0, stream>>>(
        (const void*)x, W0, dinv, mbuf, N, NHID);
    agg_h_kernel<<<abl, 256, 0, stream>>>(mbuf, col, startA, dinv, b0, hbuf, N);

    // layer 1
    gemm_mfma<128, 128, 128, 2, 2, false, true><<<g128, 256, 0, stream>>>(
        (const void*)hbuf, W1, dinv, mbuf, N, NHID);
    agg_h_kernel<<<abl, 256, 0, stream>>>(mbuf, col, startA, dinv, b1, hbuf, N);

    // layer 2 (40-wide messages)
    gemm_mfma<128, 256, 64, 4, 1, true, true><<<g256, 256, 0, stream>>>(
        (const void*)hbuf, W2, dinv, mbuf, N, NCLASS);
    agg_out_kernel<<<abl, 256, 0, stream>>>((const __half*)mbuf, col, startA, dinv, b2,
                                            out, N);
}

// Round 12
// 357.970 us; speedup vs baseline: 1.4263x; 1.0429x over previous
//
#include <hip/hip_runtime.h>
#include <hip/hip_bf16.h>
#include <hip/hip_fp16.h>
#include <math.h>

#define NHID 128
#define NCLASS 40
#define NBLK 256          // edge-chunk blocks for bucket passes
#define MAXBUK 1600       // >= ceil(N/64)

typedef _Float16 f16;
typedef f16 f16x8 __attribute__((ext_vector_type(8)));
typedef float f32x4 __attribute__((ext_vector_type(4)));

// ---------------- CSR build: 2-level counting sort (LDS atomics only) ----
// eb entries packed: (src << 6) | (dst & 63)

__global__ __launch_bounds__(256) void bucket_hist(const int* __restrict__ dst,
                                                   int* __restrict__ bh,
                                                   int E, int nbuk, int chunk) {
    __shared__ int h[MAXBUK];
    for (int i = threadIdx.x; i < nbuk; i += 256) h[i] = 0;
    __syncthreads();
    int b = blockIdx.x;
    int lo = b * chunk, hi = min(E, lo + chunk);
    for (int e = lo + threadIdx.x; e < hi; e += 256) atomicAdd(&h[dst[e] >> 6], 1);
    __syncthreads();
    for (int i = threadIdx.x; i < nbuk; i += 256) bh[(size_t)b * nbuk + i] = h[i];
}

__global__ __launch_bounds__(256) void bucket_total(const int* __restrict__ bh,
                                                    int* __restrict__ T, int nbuk) {
    int buk = blockIdx.x * 256 + threadIdx.x;
    if (buk >= nbuk) return;
    int s = 0;
    for (int b = 0; b < NBLK; ++b) s += bh[(size_t)b * nbuk + buk];
    T[buk] = s;
}

__global__ __launch_bounds__(256) void bucket_scan(const int* __restrict__ T,
                                                   int* __restrict__ BB, int nbuk, int E) {
    __shared__ int sc[256];
    __shared__ int carry;
    if (threadIdx.x == 0) carry = 0;
    __syncthreads();
    for (int base = 0; base < nbuk; base += 256) {
        int i = base + threadIdx.x;
        int v = (i < nbuk) ? T[i] : 0;
        sc[threadIdx.x] = v;
        __syncthreads();
        for (int off = 1; off < 256; off <<= 1) {
            int t = (threadIdx.x >= off) ? sc[threadIdx.x - off] : 0;
            __syncthreads();
            sc[threadIdx.x] += t;
            __syncthreads();
        }
        if (i < nbuk) BB[i] = carry + sc[threadIdx.x] - v;
        __syncthreads();
        if (threadIdx.x == 255) carry += sc[255];
        __syncthreads();
    }
    if (threadIdx.x == 0) BB[nbuk] = E;
}

__global__ __launch_bounds__(256) void bucket_expand(const int* __restrict__ bh,
                                                     const int* __restrict__ BB,
                                                     int* __restrict__ off, int nbuk) {
    int buk = blockIdx.x * 256 + threadIdx.x;
    if (buk >= nbuk) return;
    int run = BB[buk];
    for (int b = 0; b < NBLK; ++b) {
        off[(size_t)b * nbuk + buk] = run;
        run += bh[(size_t)b * nbuk + buk];
    }
}

__global__ __launch_bounds__(256) void bucket_scatter(const int* __restrict__ src,
                                                      const int* __restrict__ dst,
                                                      const int* __restrict__ off,
                                                      int* __restrict__ eb,
                                                      int E, int nbuk, int chunk) {
    __shared__ int cur[MAXBUK];
    int b = blockIdx.x;
    for (int i = threadIdx.x; i < nbuk; i += 256) cur[i] = off[(size_t)b * nbuk + i];
    __syncthreads();
    int lo = b * chunk, hi = min(E, lo + chunk);
    for (int e = lo + threadIdx.x; e < hi; e += 256) {
        int d = dst[e], s = src[e];
        int pos = atomicAdd(&cur[d >> 6], 1);
        eb[pos] = (s << 6) | (d & 63);
    }
}

__global__ __launch_bounds__(256) void bucket_csr(const int* __restrict__ eb,
                                                  const int* __restrict__ BB,
                                                  int* __restrict__ startA,
                                                  float* __restrict__ dinv,
                                                  int* __restrict__ col,
                                                  int N, int E) {
    __shared__ int h[64];
    int b = blockIdx.x;
    int bs = BB[b], be = BB[b + 1];
    if (threadIdx.x < 64) h[threadIdx.x] = 0;
    __syncthreads();
    for (int i = bs + threadIdx.x; i < be; i += 256) atomicAdd(&h[eb[i] & 63], 1);
    __syncthreads();
    if (threadIdx.x < 64) {  // wave 0
        int v = h[threadIdx.x];
        int incl = v;
#pragma unroll
        for (int o = 1; o < 64; o <<= 1) {
            int t = __shfl_up(incl, o, 64);
            if ((int)threadIdx.x >= o) incl += t;
        }
        int n = (b << 6) + threadIdx.x;
        if (n < N) {
            startA[n] = bs + incl - v;
            dinv[n] = rsqrtf((float)(v + 1));  // +1 self-loop
        }
        h[threadIdx.x] = incl - v;  // reuse as cursor
    }
    __syncthreads();
    for (int i = bs + threadIdx.x; i < be; i += 256) {
        int pk = eb[i];
        int pos = bs + atomicAdd(&h[pk & 63], 1);
        col[pos] = pk >> 6;
    }
    if (b == 0 && threadIdx.x == 0) startA[N] = E;
}

// --------------------------- MFMA GEMM (R3-proven) -----------------------
// C = dinv[row] * (A @ W), fp16 out. CST: output row stride (0 -> N).
// When CST > 0 the store is unguarded (W is zero-padded via GUARDN path,
// so pad columns hold zeros/garbage never read).
template <int K, int BM, int BN, int WM, int WN, bool GUARDN, bool AHALF, int CST>
__global__ __launch_bounds__(256) void gemm_mfma(const void* __restrict__ Ap,
                                                 const float* __restrict__ W,
                                                 const float* __restrict__ dinv,
                                                 f16* __restrict__ C, int M, int N) {
    constexpr int KC = 64;
    __shared__ f16 As[BM * KC];
    __shared__ f16 Bs[BN * KC];
    __shared__ float sdinv[BM];
    const int t = threadIdx.x;
    const int wid = t >> 6, lane = t & 63;
    const int wm = wid % WM, wn = wid / WM;
    const int row0 = blockIdx.x * BM;

    for (int i = t; i < BM; i += 256) {
        int r = row0 + i;
        sdinv[i] = dinv[r < M ? r : M - 1];
    }

    f32x4 acc[4][4] = {};

    for (int k0 = 0; k0 < K; k0 += KC) {
        if (AHALF) {
            const f16* A = (const f16*)Ap;
#pragma unroll
            for (int i = 0; i < BM / 32; ++i) {
                int g = t + i * 256;
                int r = g >> 3, c = g & 7;
                int grow = row0 + r; if (grow >= M) grow = M - 1;
                f16x8 v = *reinterpret_cast<const f16x8*>(&A[(size_t)grow * K + k0 + c * 8]);
                *reinterpret_cast<f16x8*>(&As[r * 64 + ((c ^ (r & 7)) << 3)]) = v;
            }
        } else {
            const float* A = (const float*)Ap;
#pragma unroll
            for (int i = 0; i < BM / 32; ++i) {
                int g = t + i * 256;
                int r = g >> 3, c = g & 7;
                int grow = row0 + r; if (grow >= M) grow = M - 1;
                const float* s = &A[(size_t)grow * K + k0 + c * 8];
                float4 a = *reinterpret_cast<const float4*>(s);
                float4 b = *reinterpret_cast<const float4*>(s + 4);
                f16x8 v = {(f16)a.x, (f16)a.y, (f16)a.z, (f16)a.w,
                           (f16)b.x, (f16)b.y, (f16)b.z, (f16)b.w};
                *reinterpret_cast<f16x8*>(&As[r * 64 + ((c ^ (r & 7)) << 3)]) = v;
            }
        }
        if (!GUARDN) {
#pragma unroll
            for (int i = 0; i < BN / 16; ++i) {
                int v = t + i * 256;
                int kk = v / (BN / 4), nq = v % (BN / 4);
                float4 w = *reinterpret_cast<const float4*>(&W[(size_t)(k0 + kk) * N + nq * 4]);
                float ws[4] = {w.x, w.y, w.z, w.w};
#pragma unroll
                for (int j = 0; j < 4; ++j) {
                    int n = nq * 4 + j;
                    Bs[n * 64 + (((kk >> 3) ^ (n & 7)) << 3) + (kk & 7)] = (f16)ws[j];
                }
            }
        } else {
#pragma unroll
            for (int i = 0; i < BN / 16; ++i) {
                int v = t + i * 256;
                int kk = v / (BN / 4), nq = v % (BN / 4);
#pragma unroll
                for (int j = 0; j < 4; ++j) {
                    int n = nq * 4 + j;
                    float wv = (n < N) ? W[(size_t)(k0 + kk) * N + n] : 0.f;
                    Bs[n * 64 + (((kk >> 3) ^ (n & 7)) << 3) + (kk & 7)] = (f16)wv;
                }
            }
        }
        __syncthreads();

#pragma unroll
        for (int s = 0; s < 2; ++s) {
            f16x8 af[4], bf[4];
            int c = s * 4 + (lane >> 4);
#pragma unroll
            for (int mf = 0; mf < 4; ++mf) {
                int r = wm * 64 + mf * 16 + (lane & 15);
                af[mf] = *reinterpret_cast<const f16x8*>(&As[r * 64 + ((c ^ (r & 7)) << 3)]);
            }
#pragma unroll
            for (int nf = 0; nf < 4; ++nf) {
                int n = wn * 64 + nf * 16 + (lane & 15);
                bf[nf] = *reinterpret_cast<const f16x8*>(&Bs[n * 64 + ((c ^ (n & 7)) << 3)]);
            }
#pragma unroll
            for (int mf = 0; mf < 4; ++mf)
#pragma unroll
                for (int nf = 0; nf < 4; ++nf)
                    acc[mf][nf] = __builtin_amdgcn_mfma_f32_16x16x32_f16(af[mf], bf[nf],
                                                                         acc[mf][nf], 0, 0, 0);
        }
        __syncthreads();
    }

    constexpr int OST = (CST > 0) ? CST : 0;
#pragma unroll
    for (int mf = 0; mf < 4; ++mf) {
#pragma unroll
        for (int q = 0; q < 4; ++q) {
            int lr = wm * 64 + mf * 16 + (lane >> 4) * 4 + q;
            int grow = row0 + lr;
            if (grow < M) {
                float scl = sdinv[lr];
#pragma unroll
                for (int nf = 0; nf < 4; ++nf) {
                    int gcol = wn * 64 + nf * 16 + (lane & 15);
                    if (CST > 0) {
                        C[(size_t)grow * OST + gcol] = (f16)(acc[mf][nf][q] * scl);
                    } else if (!GUARDN || gcol < N) {
                        C[(size_t)grow * N + gcol] = (f16)(acc[mf][nf][q] * scl);
                    }
                }
            }
        }
    }
}

// --------------------------- Aggregation --------------------------------
// One wave per node, 4 edges per gather instruction (eg = lane>>4 picks the
// edge, fl = lane&15 the 16B feature slot), 8 edges in flight per loop iter
// (two independent gathers + split accumulator banks). 2 shfl_xor rounds
// combine edge-group partials. Messages pre-scaled by dinv[src].
__global__ __launch_bounds__(256) void agg_h_kernel(
        const f16* __restrict__ m, const int* __restrict__ col,
        const int* __restrict__ start, const float* __restrict__ dinv,
        const float* __restrict__ bias, f16* __restrict__ out, int N) {
    int w = (int)((blockIdx.x * 256 + threadIdx.x) >> 6);
    int lane = threadIdx.x & 63;
    if (w >= N) return;
    const int eg = lane >> 4, fl = lane & 15;
    int s = start[w], e = start[w + 1];
    float a[8] = {}, b[8] = {};
    int p = s;
    int end8 = s + ((e - s) & ~7);
    for (; p < end8; p += 8) {
        int j0 = col[p + eg];
        int j1 = col[p + 4 + eg];
        f16x8 v0 = *reinterpret_cast<const f16x8*>(&m[(size_t)j0 * 128 + fl * 8]);
        f16x8 v1 = *reinterpret_cast<const f16x8*>(&m[(size_t)j1 * 128 + fl * 8]);
#pragma unroll
        for (int u = 0; u < 8; ++u) a[u] += (float)v0[u];
#pragma unroll
        for (int u = 0; u < 8; ++u) b[u] += (float)v1[u];
    }
    if (p + 4 <= e) {
        int j = col[p + eg];
        f16x8 v = *reinterpret_cast<const f16x8*>(&m[(size_t)j * 128 + fl * 8]);
#pragma unroll
        for (int u = 0; u < 8; ++u) a[u] += (float)v[u];
        p += 4;
    }
    if (p < e) {
        int idx = p + eg;
        bool val = idx < e;
        int j = col[val ? idx : s];
        f16x8 v = *reinterpret_cast<const f16x8*>(&m[(size_t)j * 128 + fl * 8]);
        if (val) {
#pragma unroll
            for (int u = 0; u < 8; ++u) b[u] += (float)v[u];
        }
    }
    if (eg == 0) {  // self-loop once
        f16x8 v = *reinterpret_cast<const f16x8*>(&m[(size_t)w * 128 + fl * 8]);
#pragma unroll
        for (int u = 0; u < 8; ++u) a[u] += (float)v[u];
    }
#pragma unroll
    for (int u = 0; u < 8; ++u) a[u] += b[u];
#pragma unroll
    for (int off = 16; off <= 32; off <<= 1)
#pragma unroll
        for (int u = 0; u < 8; ++u) a[u] += __shfl_xor(a[u], off, 64);
    if (eg == 0) {
        float di = dinv[w];
        float4 bA = *reinterpret_cast<const float4*>(&bias[fl * 8]);
        float4 bB = *reinterpret_cast<const float4*>(&bias[fl * 8 + 4]);
        float bb[8] = {bA.x, bA.y, bA.z, bA.w, bB.x, bB.y, bB.z, bB.w};
        f16x8 o;
#pragma unroll
        for (int u = 0; u < 8; ++u) o[u] = (f16)fmaxf(fmaf(di, a[u], bb[u]), 0.f);
        *reinterpret_cast<f16x8*>(&out[(size_t)w * 128 + fl * 8]) = o;
    }
}

// Final layer: lane = class, rows padded to 64 halfs (128B, 2 aligned lines
// per gather), 8-deep pipeline, wave-wide log_softmax.
__global__ __launch_bounds__(256) void agg_out_kernel(
        const __half* __restrict__ m, const int* __restrict__ col,
        const int* __restrict__ start,
        const float* __restrict__ dinv, const float* __restrict__ bias,
        float* __restrict__ out, int N) {
    int w = (int)((blockIdx.x * 256 + threadIdx.x) >> 6);
    int lane = threadIdx.x & 63;
    if (w >= N) return;
    bool act = lane < NCLASS;
    int cl = act ? lane : 0;
    int s = start[w];
    int e = start[w + 1];
    float a0 = 0.f, a1 = 0.f;
    int p = s;
    for (; p + 8 <= e; p += 8) {
        int j[8];
#pragma unroll
        for (int u = 0; u < 8; ++u) j[u] = col[p + u];
        __half v[8];
#pragma unroll
        for (int u = 0; u < 8; ++u) v[u] = m[(size_t)j[u] * 64 + cl];
#pragma unroll
        for (int u = 0; u < 8; ++u) {
            if (u & 1) a1 += __half2float(v[u]);
            else       a0 += __half2float(v[u]);
        }
    }
    for (; p < e; ++p) a0 += __half2float(m[(size_t)col[p] * 64 + cl]);
    a0 += __half2float(m[(size_t)w * 64 + cl]);
    float di = dinv[w];
    float h = fmaxf(fmaf(di, a0 + a1, bias[cl]), 0.f);
    float hm = act ? h : -INFINITY;
#pragma unroll
    for (int off = 32; off; off >>= 1) hm = fmaxf(hm, __shfl_xor(hm, off, 64));
    float ex = act ? expf(h - hm) : 0.f;
    float se = ex;
#pragma unroll
    for (int off = 32; off; off >>= 1) se += __shfl_xor(se, off, 64);
    if (act) out[(size_t)w * NCLASS + lane] = h - hm - logf(se);
}

// ------------------------------ launch -----------------------------------

extern "C" void kernel_launch(void* const* d_in, const int* in_sizes, int n_in,
                              void* d_out, int out_size, void* d_ws, size_t ws_size,
                              hipStream_t stream) {
    const float* x  = (const float*)d_in[0];
    const int*   ei = (const int*)d_in[1];
    const float* W0 = (const float*)d_in[2];
    const float* b0 = (const float*)d_in[3];
    const float* W1 = (const float*)d_in[4];
    const float* b1 = (const float*)d_in[5];
    const float* W2 = (const float*)d_in[6];
    const float* b2 = (const float*)d_in[7];
    float* out = (float*)d_out;

    const int NFEATr = 256;
    const int N = in_sizes[0] / NFEATr;  // 100000
    const int E = in_sizes[1] / 2;       // 1600000
    const int* src = ei;
    const int* dst = ei + E;

    const int nbuk = (N + 63) >> 6;      // 1563
    const int chunk = (E + NBLK - 1) / NBLK;

    char* p = (char*)d_ws;
    auto alloc = [&](size_t bytes) -> void* {
        void* r = (void*)p;
        p += (bytes + 255) & ~(size_t)255;
        return r;
    };
    int*    bh     = (int*)alloc((size_t)NBLK * nbuk * 4);
    int*    T      = (int*)alloc((size_t)nbuk * 4);
    int*    BB     = (int*)alloc((size_t)(nbuk + 1) * 4);
    int*    offb   = (int*)alloc((size_t)NBLK * nbuk * 4);
    int*    eb     = (int*)alloc((size_t)E * 4);
    int*    col    = (int*)alloc((size_t)E * 4);
    int*    startA = (int*)alloc((size_t)(N + 1) * 4);
    float*  dinv   = (float*)alloc((size_t)N * 4);
    f16*    mbuf   = (f16*)alloc((size_t)N * NHID * 2);
    f16*    hbuf   = (f16*)alloc((size_t)N * NHID * 2);
    f16*    m2buf  = (f16*)alloc((size_t)N * 64 * 2);   // padded 64-wide layer-2 msgs

    int nbl7 = (nbuk + 255) / 256;

    bucket_hist<<<NBLK, 256, 0, stream>>>(dst, bh, E, nbuk, chunk);
    bucket_total<<<nbl7, 256, 0, stream>>>(bh, T, nbuk);
    bucket_scan<<<1, 256, 0, stream>>>(T, BB, nbuk, E);
    bucket_expand<<<nbl7, 256, 0, stream>>>(bh, BB, offb, nbuk);
    bucket_scatter<<<NBLK, 256, 0, stream>>>(src, dst, offb, eb, E, nbuk, chunk);
    bucket_csr<<<nbuk, 256, 0, stream>>>(eb, BB, startA, dinv, col, N, E);

    int abl = (N + 3) / 4;
    int g128 = (N + 127) / 128;
    int g256 = (N + 255) / 256;

    // layer 0: x fp32 [N,256] @ W0 -> mbuf f16 (prescaled by dinv[row])
    gemm_mfma<256, 128, 128, 2, 2, false, false, 0><<<g128, 256, 0, stream>>>(
        (const void*)x, W0, dinv, mbuf, N, NHID);
    agg_h_kernel<<<abl, 256, 0, stream>>>(mbuf, col, startA, dinv, b0, hbuf, N);

    // layer 1
    gemm_mfma<128, 128, 128, 2, 2, false, true, 0><<<g128, 256, 0, stream>>>(
        (const void*)hbuf, W1, dinv, mbuf, N, NHID);
    agg_h_kernel<<<abl, 256, 0, stream>>>(mbuf, col, startA, dinv, b1, hbuf, N);

    // layer 2 (40-wide messages, padded to stride 64)
    gemm_mfma<128, 256, 64, 4, 1, true, true, 64><<<g256, 256, 0, stream>>>(
        (const void*)hbuf, W2, dinv, m2buf, N, NCLASS);
    agg_out_kernel<<<abl, 256, 0, stream>>>((const __half*)m2buf, col, startA, dinv, b2,
                                            out, N);
}

// Round 13
// 349.414 us; speedup vs baseline: 1.4612x; 1.0245x over previous
//
#include <hip/hip_runtime.h>
#include <hip/hip_bf16.h>
#include <hip/hip_fp16.h>
#include <math.h>

#define NHID 128
#define NCLASS 40
#define NBLK 256          // edge-chunk blocks for bucket passes
#define MAXBUK 1600       // >= ceil(N/64)

typedef _Float16 f16;
typedef f16 f16x8 __attribute__((ext_vector_type(8)));
typedef float f32x4 __attribute__((ext_vector_type(4)));

// ---------------- CSR build: 2-level counting sort (LDS atomics only) ----
// eb entries packed: (src << 6) | (dst & 63)

__global__ __launch_bounds__(256) void bucket_hist(const int* __restrict__ dst,
                                                   int* __restrict__ bh,
                                                   int E, int nbuk, int chunk) {
    __shared__ int h[MAXBUK];
    for (int i = threadIdx.x; i < nbuk; i += 256) h[i] = 0;
    __syncthreads();
    int b = blockIdx.x;
    int lo = b * chunk, hi = min(E, lo + chunk);
    for (int e = lo + threadIdx.x; e < hi; e += 256) atomicAdd(&h[dst[e] >> 6], 1);
    __syncthreads();
    for (int i = threadIdx.x; i < nbuk; i += 256) bh[(size_t)b * nbuk + i] = h[i];
}

__global__ __launch_bounds__(256) void bucket_total(const int* __restrict__ bh,
                                                    int* __restrict__ T, int nbuk) {
    int buk = blockIdx.x * 256 + threadIdx.x;
    if (buk >= nbuk) return;
    int s = 0;
    for (int b = 0; b < NBLK; ++b) s += bh[(size_t)b * nbuk + buk];
    T[buk] = s;
}

__global__ __launch_bounds__(256) void bucket_scan(const int* __restrict__ T,
                                                   int* __restrict__ BB, int nbuk, int E) {
    __shared__ int sc[256];
    __shared__ int carry;
    if (threadIdx.x == 0) carry = 0;
    __syncthreads();
    for (int base = 0; base < nbuk; base += 256) {
        int i = base + threadIdx.x;
        int v = (i < nbuk) ? T[i] : 0;
        sc[threadIdx.x] = v;
        __syncthreads();
        for (int off = 1; off < 256; off <<= 1) {
            int t = (threadIdx.x >= off) ? sc[threadIdx.x - off] : 0;
            __syncthreads();
            sc[threadIdx.x] += t;
            __syncthreads();
        }
        if (i < nbuk) BB[i] = carry + sc[threadIdx.x] - v;
        __syncthreads();
        if (threadIdx.x == 255) carry += sc[255];
        __syncthreads();
    }
    if (threadIdx.x == 0) BB[nbuk] = E;
}

__global__ __launch_bounds__(256) void bucket_expand(const int* __restrict__ bh,
                                                     const int* __restrict__ BB,
                                                     int* __restrict__ off, int nbuk) {
    int buk = blockIdx.x * 256 + threadIdx.x;
    if (buk >= nbuk) return;
    int run = BB[buk];
    for (int b = 0; b < NBLK; ++b) {
        off[(size_t)b * nbuk + buk] = run;
        run += bh[(size_t)b * nbuk + buk];
    }
}

__global__ __launch_bounds__(256) void bucket_scatter(const int* __restrict__ src,
                                                      const int* __restrict__ dst,
                                                      const int* __restrict__ off,
                                                      int* __restrict__ eb,
                                                      int E, int nbuk, int chunk) {
    __shared__ int cur[MAXBUK];
    int b = blockIdx.x;
    for (int i = threadIdx.x; i < nbuk; i += 256) cur[i] = off[(size_t)b * nbuk + i];
    __syncthreads();
    int lo = b * chunk, hi = min(E, lo + chunk);
    for (int e = lo + threadIdx.x; e < hi; e += 256) {
        int d = dst[e], s = src[e];
        int pos = atomicAdd(&cur[d >> 6], 1);
        eb[pos] = (s << 6) | (d & 63);
    }
}

__global__ __launch_bounds__(256) void bucket_csr(const int* __restrict__ eb,
                                                  const int* __restrict__ BB,
                                                  int* __restrict__ startA,
                                                  float* __restrict__ dinv,
                                                  int* __restrict__ col,
                                                  int N, int E) {
    __shared__ int h[64];
    int b = blockIdx.x;
    int bs = BB[b], be = BB[b + 1];
    if (threadIdx.x < 64) h[threadIdx.x] = 0;
    __syncthreads();
    for (int i = bs + threadIdx.x; i < be; i += 256) atomicAdd(&h[eb[i] & 63], 1);
    __syncthreads();
    if (threadIdx.x < 64) {  // wave 0
        int v = h[threadIdx.x];
        int incl = v;
#pragma unroll
        for (int o = 1; o < 64; o <<= 1) {
            int t = __shfl_up(incl, o, 64);
            if ((int)threadIdx.x >= o) incl += t;
        }
        int n = (b << 6) + threadIdx.x;
        if (n < N) {
            startA[n] = bs + incl - v;
            dinv[n] = rsqrtf((float)(v + 1));  // +1 self-loop
        }
        h[threadIdx.x] = incl - v;  // reuse as cursor
    }
    __syncthreads();
    for (int i = bs + threadIdx.x; i < be; i += 256) {
        int pk = eb[i];
        int pos = bs + atomicAdd(&h[pk & 63], 1);
        col[pos] = pk >> 6;
    }
    if (b == 0 && threadIdx.x == 0) startA[N] = E;
}

// --------------------------- MFMA GEMM (R3-proven) -----------------------
// C = dinv[row] * (A @ W), fp16 out. CST: output row stride (0 -> N).
// When CST > 0 the store is unguarded (W is zero-padded via GUARDN path,
// so pad columns hold exact zeros).
template <int K, int BM, int BN, int WM, int WN, bool GUARDN, bool AHALF, int CST>
__global__ __launch_bounds__(256) void gemm_mfma(const void* __restrict__ Ap,
                                                 const float* __restrict__ W,
                                                 const float* __restrict__ dinv,
                                                 f16* __restrict__ C, int M, int N) {
    constexpr int KC = 64;
    __shared__ f16 As[BM * KC];
    __shared__ f16 Bs[BN * KC];
    __shared__ float sdinv[BM];
    const int t = threadIdx.x;
    const int wid = t >> 6, lane = t & 63;
    const int wm = wid % WM, wn = wid / WM;
    const int row0 = blockIdx.x * BM;

    for (int i = t; i < BM; i += 256) {
        int r = row0 + i;
        sdinv[i] = dinv[r < M ? r : M - 1];
    }

    f32x4 acc[4][4] = {};

    for (int k0 = 0; k0 < K; k0 += KC) {
        if (AHALF) {
            const f16* A = (const f16*)Ap;
#pragma unroll
            for (int i = 0; i < BM / 32; ++i) {
                int g = t + i * 256;
                int r = g >> 3, c = g & 7;
                int grow = row0 + r; if (grow >= M) grow = M - 1;
                f16x8 v = *reinterpret_cast<const f16x8*>(&A[(size_t)grow * K + k0 + c * 8]);
                *reinterpret_cast<f16x8*>(&As[r * 64 + ((c ^ (r & 7)) << 3)]) = v;
            }
        } else {
            const float* A = (const float*)Ap;
#pragma unroll
            for (int i = 0; i < BM / 32; ++i) {
                int g = t + i * 256;
                int r = g >> 3, c = g & 7;
                int grow = row0 + r; if (grow >= M) grow = M - 1;
                const float* s = &A[(size_t)grow * K + k0 + c * 8];
                float4 a = *reinterpret_cast<const float4*>(s);
                float4 b = *reinterpret_cast<const float4*>(s + 4);
                f16x8 v = {(f16)a.x, (f16)a.y, (f16)a.z, (f16)a.w,
                           (f16)b.x, (f16)b.y, (f16)b.z, (f16)b.w};
                *reinterpret_cast<f16x8*>(&As[r * 64 + ((c ^ (r & 7)) << 3)]) = v;
            }
        }
        if (!GUARDN) {
#pragma unroll
            for (int i = 0; i < BN / 16; ++i) {
                int v = t + i * 256;
                int kk = v / (BN / 4), nq = v % (BN / 4);
                float4 w = *reinterpret_cast<const float4*>(&W[(size_t)(k0 + kk) * N + nq * 4]);
                float ws[4] = {w.x, w.y, w.z, w.w};
#pragma unroll
                for (int j = 0; j < 4; ++j) {
                    int n = nq * 4 + j;
                    Bs[n * 64 + (((kk >> 3) ^ (n & 7)) << 3) + (kk & 7)] = (f16)ws[j];
                }
            }
        } else {
#pragma unroll
            for (int i = 0; i < BN / 16; ++i) {
                int v = t + i * 256;
                int kk = v / (BN / 4), nq = v % (BN / 4);
#pragma unroll
                for (int j = 0; j < 4; ++j) {
                    int n = nq * 4 + j;
                    float wv = (n < N) ? W[(size_t)(k0 + kk) * N + n] : 0.f;
                    Bs[n * 64 + (((kk >> 3) ^ (n & 7)) << 3) + (kk & 7)] = (f16)wv;
                }
            }
        }
        __syncthreads();

#pragma unroll
        for (int s = 0; s < 2; ++s) {
            f16x8 af[4], bf[4];
            int c = s * 4 + (lane >> 4);
#pragma unroll
            for (int mf = 0; mf < 4; ++mf) {
                int r = wm * 64 + mf * 16 + (lane & 15);
                af[mf] = *reinterpret_cast<const f16x8*>(&As[r * 64 + ((c ^ (r & 7)) << 3)]);
            }
#pragma unroll
            for (int nf = 0; nf < 4; ++nf) {
                int n = wn * 64 + nf * 16 + (lane & 15);
                bf[nf] = *reinterpret_cast<const f16x8*>(&Bs[n * 64 + ((c ^ (n & 7)) << 3)]);
            }
#pragma unroll
            for (int mf = 0; mf < 4; ++mf)
#pragma unroll
                for (int nf = 0; nf < 4; ++nf)
                    acc[mf][nf] = __builtin_amdgcn_mfma_f32_16x16x32_f16(af[mf], bf[nf],
                                                                         acc[mf][nf], 0, 0, 0);
        }
        __syncthreads();
    }

    constexpr int OST = (CST > 0) ? CST : 0;
#pragma unroll
    for (int mf = 0; mf < 4; ++mf) {
#pragma unroll
        for (int q = 0; q < 4; ++q) {
            int lr = wm * 64 + mf * 16 + (lane >> 4) * 4 + q;
            int grow = row0 + lr;
            if (grow < M) {
                float scl = sdinv[lr];
#pragma unroll
                for (int nf = 0; nf < 4; ++nf) {
                    int gcol = wn * 64 + nf * 16 + (lane & 15);
                    if (CST > 0) {
                        C[(size_t)grow * OST + gcol] = (f16)(acc[mf][nf][q] * scl);
                    } else if (!GUARDN || gcol < N) {
                        C[(size_t)grow * N + gcol] = (f16)(acc[mf][nf][q] * scl);
                    }
                }
            }
        }
    }
}

// --------------------------- Aggregation --------------------------------
// One wave per node, 4 edges per gather instruction (eg = lane>>4 picks the
// edge, fl = lane&15 the 16B feature slot), 8 edges in flight per loop iter.
__global__ __launch_bounds__(256) void agg_h_kernel(
        const f16* __restrict__ m, const int* __restrict__ col,
        const int* __restrict__ start, const float* __restrict__ dinv,
        const float* __restrict__ bias, f16* __restrict__ out, int N) {
    int w = (int)((blockIdx.x * 256 + threadIdx.x) >> 6);
    int lane = threadIdx.x & 63;
    if (w >= N) return;
    const int eg = lane >> 4, fl = lane & 15;
    int s = start[w], e = start[w + 1];
    float a[8] = {}, b[8] = {};
    int p = s;
    int end8 = s + ((e - s) & ~7);
    for (; p < end8; p += 8) {
        int j0 = col[p + eg];
        int j1 = col[p + 4 + eg];
        f16x8 v0 = *reinterpret_cast<const f16x8*>(&m[(size_t)j0 * 128 + fl * 8]);
        f16x8 v1 = *reinterpret_cast<const f16x8*>(&m[(size_t)j1 * 128 + fl * 8]);
#pragma unroll
        for (int u = 0; u < 8; ++u) a[u] += (float)v0[u];
#pragma unroll
        for (int u = 0; u < 8; ++u) b[u] += (float)v1[u];
    }
    if (p + 4 <= e) {
        int j = col[p + eg];
        f16x8 v = *reinterpret_cast<const f16x8*>(&m[(size_t)j * 128 + fl * 8]);
#pragma unroll
        for (int u = 0; u < 8; ++u) a[u] += (float)v[u];
        p += 4;
    }
    if (p < e) {
        int idx = p + eg;
        bool val = idx < e;
        int j = col[val ? idx : s];
        f16x8 v = *reinterpret_cast<const f16x8*>(&m[(size_t)j * 128 + fl * 8]);
        if (val) {
#pragma unroll
            for (int u = 0; u < 8; ++u) b[u] += (float)v[u];
        }
    }
    if (eg == 0) {  // self-loop once
        f16x8 v = *reinterpret_cast<const f16x8*>(&m[(size_t)w * 128 + fl * 8]);
#pragma unroll
        for (int u = 0; u < 8; ++u) a[u] += (float)v[u];
    }
#pragma unroll
    for (int u = 0; u < 8; ++u) a[u] += b[u];
#pragma unroll
    for (int off = 16; off <= 32; off <<= 1)
#pragma unroll
        for (int u = 0; u < 8; ++u) a[u] += __shfl_xor(a[u], off, 64);
    if (eg == 0) {
        float di = dinv[w];
        float4 bA = *reinterpret_cast<const float4*>(&bias[fl * 8]);
        float4 bB = *reinterpret_cast<const float4*>(&bias[fl * 8 + 4]);
        float bb[8] = {bA.x, bA.y, bA.z, bA.w, bB.x, bB.y, bB.z, bB.w};
        f16x8 o;
#pragma unroll
        for (int u = 0; u < 8; ++u) o[u] = (f16)fmaxf(fmaf(di, a[u], bb[u]), 0.f);
        *reinterpret_cast<f16x8*>(&out[(size_t)w * 128 + fl * 8]) = o;
    }
}

// Final layer: padded 64-half rows; 8 lanes x 16B per edge -> 8 edges per
// gather instruction, exactly 2 aligned lines/edge. Edge-group reduce via
// 3 shfl_xor rounds (8/16/32); classes = fl*8..fl*8+7 (fl<5 real, 5x8=40);
// softmax over class slots via 3 intra-group shuffles (1/2/4).
__global__ __launch_bounds__(256) void agg_out_kernel(
        const f16* __restrict__ m, const int* __restrict__ col,
        const int* __restrict__ start,
        const float* __restrict__ dinv, const float* __restrict__ bias,
        float* __restrict__ out, int N) {
    int w = (int)((blockIdx.x * 256 + threadIdx.x) >> 6);
    int lane = threadIdx.x & 63;
    if (w >= N) return;
    const int eg = lane >> 3, fl = lane & 7;
    const bool act = fl < 5;  // fl*8 .. fl*8+7 all < 40
    int s = start[w], e = start[w + 1];
    float a[8] = {};
    int p = s;
    int end8 = s + ((e - s) & ~7);
    for (; p < end8; p += 8) {
        int j = col[p + eg];
        f16x8 v = *reinterpret_cast<const f16x8*>(&m[(size_t)j * 64 + fl * 8]);
#pragma unroll
        for (int u = 0; u < 8; ++u) a[u] += (float)v[u];
    }
    if (p < e) {
        int idx = p + eg;
        bool val = idx < e;
        int j = col[val ? idx : s];
        f16x8 v = *reinterpret_cast<const f16x8*>(&m[(size_t)j * 64 + fl * 8]);
        if (val) {
#pragma unroll
            for (int u = 0; u < 8; ++u) a[u] += (float)v[u];
        }
    }
    if (eg == 0) {  // self-loop once
        f16x8 v = *reinterpret_cast<const f16x8*>(&m[(size_t)w * 64 + fl * 8]);
#pragma unroll
        for (int u = 0; u < 8; ++u) a[u] += (float)v[u];
    }
#pragma unroll
    for (int off = 8; off <= 32; off <<= 1)
#pragma unroll
        for (int u = 0; u < 8; ++u) a[u] += __shfl_xor(a[u], off, 64);
    // bias + relu per class slot
    float di = dinv[w];
    float h[8];
    float mx = -INFINITY;
    if (act) {
        float4 bA = *reinterpret_cast<const float4*>(&bias[fl * 8]);
        float4 bB = *reinterpret_cast<const float4*>(&bias[fl * 8 + 4]);
        float bb[8] = {bA.x, bA.y, bA.z, bA.w, bB.x, bB.y, bB.z, bB.w};
#pragma unroll
        for (int u = 0; u < 8; ++u) {
            h[u] = fmaxf(fmaf(di, a[u], bb[u]), 0.f);
            mx = fmaxf(mx, h[u]);
        }
    }
#pragma unroll
    for (int off = 1; off <= 4; off <<= 1) mx = fmaxf(mx, __shfl_xor(mx, off, 64));
    float se = 0.f;
    if (act) {
#pragma unroll
        for (int u = 0; u < 8; ++u) se += expf(h[u] - mx);
    }
#pragma unroll
    for (int off = 1; off <= 4; off <<= 1) se += __shfl_xor(se, off, 64);
    if (eg == 0 && act) {
        float ls = logf(se);
        float4 o0 = make_float4(h[0] - mx - ls, h[1] - mx - ls, h[2] - mx - ls, h[3] - mx - ls);
        float4 o1 = make_float4(h[4] - mx - ls, h[5] - mx - ls, h[6] - mx - ls, h[7] - mx - ls);
        *reinterpret_cast<float4*>(&out[(size_t)w * NCLASS + fl * 8]) = o0;
        *reinterpret_cast<float4*>(&out[(size_t)w * NCLASS + fl * 8 + 4]) = o1;
    }
}

// ------------------------------ launch -----------------------------------

extern "C" void kernel_launch(void* const* d_in, const int* in_sizes, int n_in,
                              void* d_out, int out_size, void* d_ws, size_t ws_size,
                              hipStream_t stream) {
    const float* x  = (const float*)d_in[0];
    const int*   ei = (const int*)d_in[1];
    const float* W0 = (const float*)d_in[2];
    const float* b0 = (const float*)d_in[3];
    const float* W1 = (const float*)d_in[4];
    const float* b1 = (const float*)d_in[5];
    const float* W2 = (const float*)d_in[6];
    const float* b2 = (const float*)d_in[7];
    float* out = (float*)d_out;

    const int NFEATr = 256;
    const int N = in_sizes[0] / NFEATr;  // 100000
    const int E = in_sizes[1] / 2;       // 1600000
    const int* src = ei;
    const int* dst = ei + E;

    const int nbuk = (N + 63) >> 6;      // 1563
    const int chunk = (E + NBLK - 1) / NBLK;

    char* p = (char*)d_ws;
    auto alloc = [&](size_t bytes) -> void* {
        void* r = (void*)p;
        p += (bytes + 255) & ~(size_t)255;
        return r;
    };
    int*    bh     = (int*)alloc((size_t)NBLK * nbuk * 4);
    int*    T      = (int*)alloc((size_t)nbuk * 4);
    int*    BB     = (int*)alloc((size_t)(nbuk + 1) * 4);
    int*    offb   = (int*)alloc((size_t)NBLK * nbuk * 4);
    int*    eb     = (int*)alloc((size_t)E * 4);
    int*    col    = (int*)alloc((size_t)E * 4);
    int*    startA = (int*)alloc((size_t)(N + 1) * 4);
    float*  dinv   = (float*)alloc((size_t)N * 4);
    f16*    mbuf   = (f16*)alloc((size_t)N * NHID * 2);
    f16*    hbuf   = (f16*)alloc((size_t)N * NHID * 2);
    f16*    m2buf  = (f16*)alloc((size_t)N * 64 * 2);   // padded 64-wide layer-2 msgs

    int nbl7 = (nbuk + 255) / 256;

    bucket_hist<<<NBLK, 256, 0, stream>>>(dst, bh, E, nbuk, chunk);
    bucket_total<<<nbl7, 256, 0, stream>>>(bh, T, nbuk);
    bucket_scan<<<1, 256, 0, stream>>>(T, BB, nbuk, E);
    bucket_expand<<<nbl7, 256, 0, stream>>>(bh, BB, offb, nbuk);
    bucket_scatter<<<NBLK, 256, 0, stream>>>(src, dst, offb, eb, E, nbuk, chunk);
    bucket_csr<<<nbuk, 256, 0, stream>>>(eb, BB, startA, dinv, col, N, E);

    int abl = (N + 3) / 4;
    int g128 = (N + 127) / 128;
    int g256 = (N + 255) / 256;

    // layer 0: x fp32 [N,256] @ W0 -> mbuf f16 (prescaled by dinv[row])
    gemm_mfma<256, 128, 128, 2, 2, false, false, 0><<<g128, 256, 0, stream>>>(
        (const void*)x, W0, dinv, mbuf, N, NHID);
    agg_h_kernel<<<abl, 256, 0, stream>>>(mbuf, col, startA, dinv, b0, hbuf, N);

    // layer 1
    gemm_mfma<128, 128, 128, 2, 2, false, true, 0><<<g128, 256, 0, stream>>>(
        (const void*)hbuf, W1, dinv, mbuf, N, NHID);
    agg_h_kernel<<<abl, 256, 0, stream>>>(mbuf, col, startA, dinv, b1, hbuf, N);

    // layer 2 (40-wide messages, padded to stride 64, pads exact zero)
    gemm_mfma<128, 256, 64, 4, 1, true, true, 64><<<g256, 256, 0, stream>>>(
        (const void*)hbuf, W2, dinv, m2buf, N, NCLASS);
    agg_out_kernel<<<abl, 256, 0, stream>>>(m2buf, col, startA, dinv, b2, out, N);
}

// Round 14
// 338.277 us; speedup vs baseline: 1.5093x; 1.0329x over previous
//
#include <hip/hip_runtime.h>
#include <hip/hip_bf16.h>
#include <hip/hip_fp16.h>
#include <math.h>

#define NHID 128
#define NCLASS 40
#define NBLK 256          // edge-chunk blocks for bucket passes
#define MAXBUK 1600       // >= ceil(N/64)

typedef _Float16 f16;
typedef f16 f16x8 __attribute__((ext_vector_type(8)));
typedef f16 f16x2 __attribute__((ext_vector_type(2)));
typedef float f32x4 __attribute__((ext_vector_type(4)));

__device__ inline void pk_reduce_xor(f16x8& a, int off) {
    f16x2* a2 = reinterpret_cast<f16x2*>(&a);
#pragma unroll
    for (int k = 0; k < 4; ++k) {
        unsigned int wv = __shfl_xor(*reinterpret_cast<unsigned int*>(&a2[k]), off, 64);
        a2[k] += *reinterpret_cast<f16x2*>(&wv);
    }
}

// ---------------- CSR build: 2-level counting sort (LDS atomics only) ----
// eb entries packed: (src << 6) | (dst & 63)

__global__ __launch_bounds__(256) void bucket_hist(const int* __restrict__ dst,
                                                   int* __restrict__ bh,
                                                   int E, int nbuk, int chunk) {
    __shared__ int h[MAXBUK];
    for (int i = threadIdx.x; i < nbuk; i += 256) h[i] = 0;
    __syncthreads();
    int b = blockIdx.x;
    int lo = b * chunk, hi = min(E, lo + chunk);
    for (int e = lo + threadIdx.x; e < hi; e += 256) atomicAdd(&h[dst[e] >> 6], 1);
    __syncthreads();
    for (int i = threadIdx.x; i < nbuk; i += 256) bh[(size_t)b * nbuk + i] = h[i];
}

__global__ __launch_bounds__(256) void bucket_total(const int* __restrict__ bh,
                                                    int* __restrict__ T, int nbuk) {
    int buk = blockIdx.x * 256 + threadIdx.x;
    if (buk >= nbuk) return;
    int s = 0;
    for (int b = 0; b < NBLK; ++b) s += bh[(size_t)b * nbuk + buk];
    T[buk] = s;
}

__global__ __launch_bounds__(256) void bucket_scan(const int* __restrict__ T,
                                                   int* __restrict__ BB, int nbuk, int E) {
    __shared__ int sc[256];
    __shared__ int carry;
    if (threadIdx.x == 0) carry = 0;
    __syncthreads();
    for (int base = 0; base < nbuk; base += 256) {
        int i = base + threadIdx.x;
        int v = (i < nbuk) ? T[i] : 0;
        sc[threadIdx.x] = v;
        __syncthreads();
        for (int off = 1; off < 256; off <<= 1) {
            int t = (threadIdx.x >= off) ? sc[threadIdx.x - off] : 0;
            __syncthreads();
            sc[threadIdx.x] += t;
            __syncthreads();
        }
        if (i < nbuk) BB[i] = carry + sc[threadIdx.x] - v;
        __syncthreads();
        if (threadIdx.x == 255) carry += sc[255];
        __syncthreads();
    }
    if (threadIdx.x == 0) BB[nbuk] = E;
}

// One wave per bucket: lane l holds blocks 4l..4l+3, wave shfl scan.
__global__ __launch_bounds__(256) void bucket_expand(const int* __restrict__ bh,
                                                     const int* __restrict__ BB,
                                                     int* __restrict__ off, int nbuk) {
    int buk = blockIdx.x * 4 + (threadIdx.x >> 6);
    int lane = threadIdx.x & 63;
    if (buk >= nbuk) return;
    int v[4];
#pragma unroll
    for (int k = 0; k < 4; ++k) v[k] = bh[(size_t)(lane * 4 + k) * nbuk + buk];
    int lsum = v[0] + v[1] + v[2] + v[3];
    int incl = lsum;
#pragma unroll
    for (int o = 1; o < 64; o <<= 1) {
        int t = __shfl_up(incl, o, 64);
        if (lane >= o) incl += t;
    }
    int run = incl - lsum + BB[buk];
#pragma unroll
    for (int k = 0; k < 4; ++k) {
        off[(size_t)(lane * 4 + k) * nbuk + buk] = run;
        run += v[k];
    }
}

__global__ __launch_bounds__(256) void bucket_scatter(const int* __restrict__ src,
                                                      const int* __restrict__ dst,
                                                      const int* __restrict__ off,
                                                      int* __restrict__ eb,
                                                      int E, int nbuk, int chunk) {
    __shared__ int cur[MAXBUK];
    int b = blockIdx.x;
    for (int i = threadIdx.x; i < nbuk; i += 256) cur[i] = off[(size_t)b * nbuk + i];
    __syncthreads();
    int lo = b * chunk, hi = min(E, lo + chunk);
    for (int e = lo + threadIdx.x; e < hi; e += 256) {
        int d = dst[e], s = src[e];
        int pos = atomicAdd(&cur[d >> 6], 1);
        eb[pos] = (s << 6) | (d & 63);
    }
}

__global__ __launch_bounds__(256) void bucket_csr(const int* __restrict__ eb,
                                                  const int* __restrict__ BB,
                                                  int* __restrict__ startA,
                                                  float* __restrict__ dinv,
                                                  int* __restrict__ col,
                                                  int N, int E) {
    __shared__ int h[64];
    int b = blockIdx.x;
    int bs = BB[b], be = BB[b + 1];
    if (threadIdx.x < 64) h[threadIdx.x] = 0;
    __syncthreads();
    for (int i = bs + threadIdx.x; i < be; i += 256) atomicAdd(&h[eb[i] & 63], 1);
    __syncthreads();
    if (threadIdx.x < 64) {  // wave 0
        int v = h[threadIdx.x];
        int incl = v;
#pragma unroll
        for (int o = 1; o < 64; o <<= 1) {
            int t = __shfl_up(incl, o, 64);
            if ((int)threadIdx.x >= o) incl += t;
        }
        int n = (b << 6) + threadIdx.x;
        if (n < N) {
            startA[n] = bs + incl - v;
            dinv[n] = rsqrtf((float)(v + 1));  // +1 self-loop
        }
        h[threadIdx.x] = incl - v;  // reuse as cursor
    }
    __syncthreads();
    for (int i = bs + threadIdx.x; i < be; i += 256) {
        int pk = eb[i];
        int pos = bs + atomicAdd(&h[pk & 63], 1);
        col[pos] = pk >> 6;
    }
    if (b == 0 && threadIdx.x == 0) startA[N] = E;
}

// --------------------------- MFMA GEMM (R3-proven) -----------------------
// C = dinv[row] * (A @ W), fp16 out. CST: output row stride (0 -> N).
template <int K, int BM, int BN, int WM, int WN, bool GUARDN, bool AHALF, int CST>
__global__ __launch_bounds__(256) void gemm_mfma(const void* __restrict__ Ap,
                                                 const float* __restrict__ W,
                                                 const float* __restrict__ dinv,
                                                 f16* __restrict__ C, int M, int N) {
    constexpr int KC = 64;
    __shared__ f16 As[BM * KC];
    __shared__ f16 Bs[BN * KC];
    __shared__ float sdinv[BM];
    const int t = threadIdx.x;
    const int wid = t >> 6, lane = t & 63;
    const int wm = wid % WM, wn = wid / WM;
    const int row0 = blockIdx.x * BM;

    for (int i = t; i < BM; i += 256) {
        int r = row0 + i;
        sdinv[i] = dinv[r < M ? r : M - 1];
    }

    f32x4 acc[4][4] = {};

    for (int k0 = 0; k0 < K; k0 += KC) {
        if (AHALF) {
            const f16* A = (const f16*)Ap;
#pragma unroll
            for (int i = 0; i < BM / 32; ++i) {
                int g = t + i * 256;
                int r = g >> 3, c = g & 7;
                int grow = row0 + r; if (grow >= M) grow = M - 1;
                f16x8 v = *reinterpret_cast<const f16x8*>(&A[(size_t)grow * K + k0 + c * 8]);
                *reinterpret_cast<f16x8*>(&As[r * 64 + ((c ^ (r & 7)) << 3)]) = v;
            }
        } else {
            const float* A = (const float*)Ap;
#pragma unroll
            for (int i = 0; i < BM / 32; ++i) {
                int g = t + i * 256;
                int r = g >> 3, c = g & 7;
                int grow = row0 + r; if (grow >= M) grow = M - 1;
                const float* s = &A[(size_t)grow * K + k0 + c * 8];
                float4 a = *reinterpret_cast<const float4*>(s);
                float4 b = *reinterpret_cast<const float4*>(s + 4);
                f16x8 v = {(f16)a.x, (f16)a.y, (f16)a.z, (f16)a.w,
                           (f16)b.x, (f16)b.y, (f16)b.z, (f16)b.w};
                *reinterpret_cast<f16x8*>(&As[r * 64 + ((c ^ (r & 7)) << 3)]) = v;
            }
        }
        if (!GUARDN) {
#pragma unroll
            for (int i = 0; i < BN / 16; ++i) {
                int v = t + i * 256;
                int kk = v / (BN / 4), nq = v % (BN / 4);
                float4 w = *reinterpret_cast<const float4*>(&W[(size_t)(k0 + kk) * N + nq * 4]);
                float ws[4] = {w.x, w.y, w.z, w.w};
#pragma unroll
                for (int j = 0; j < 4; ++j) {
                    int n = nq * 4 + j;
                    Bs[n * 64 + (((kk >> 3) ^ (n & 7)) << 3) + (kk & 7)] = (f16)ws[j];
                }
            }
        } else {
#pragma unroll
            for (int i = 0; i < BN / 16; ++i) {
                int v = t + i * 256;
                int kk = v / (BN / 4), nq = v % (BN / 4);
#pragma unroll
                for (int j = 0; j < 4; ++j) {
                    int n = nq * 4 + j;
                    float wv = (n < N) ? W[(size_t)(k0 + kk) * N + n] : 0.f;
                    Bs[n * 64 + (((kk >> 3) ^ (n & 7)) << 3) + (kk & 7)] = (f16)wv;
                }
            }
        }
        __syncthreads();

#pragma unroll
        for (int s = 0; s < 2; ++s) {
            f16x8 af[4], bf[4];
            int c = s * 4 + (lane >> 4);
#pragma unroll
            for (int mf = 0; mf < 4; ++mf) {
                int r = wm * 64 + mf * 16 + (lane & 15);
                af[mf] = *reinterpret_cast<const f16x8*>(&As[r * 64 + ((c ^ (r & 7)) << 3)]);
            }
#pragma unroll
            for (int nf = 0; nf < 4; ++nf) {
                int n = wn * 64 + nf * 16 + (lane & 15);
                bf[nf] = *reinterpret_cast<const f16x8*>(&Bs[n * 64 + ((c ^ (n & 7)) << 3)]);
            }
#pragma unroll
            for (int mf = 0; mf < 4; ++mf)
#pragma unroll
                for (int nf = 0; nf < 4; ++nf)
                    acc[mf][nf] = __builtin_amdgcn_mfma_f32_16x16x32_f16(af[mf], bf[nf],
                                                                         acc[mf][nf], 0, 0, 0);
        }
        __syncthreads();
    }

    constexpr int OST = (CST > 0) ? CST : 0;
#pragma unroll
    for (int mf = 0; mf < 4; ++mf) {
#pragma unroll
        for (int q = 0; q < 4; ++q) {
            int lr = wm * 64 + mf * 16 + (lane >> 4) * 4 + q;
            int grow = row0 + lr;
            if (grow < M) {
                float scl = sdinv[lr];
#pragma unroll
                for (int nf = 0; nf < 4; ++nf) {
                    int gcol = wn * 64 + nf * 16 + (lane & 15);
                    if (CST > 0) {
                        C[(size_t)grow * OST + gcol] = (f16)(acc[mf][nf][q] * scl);
                    } else if (!GUARDN || gcol < N) {
                        C[(size_t)grow * N + gcol] = (f16)(acc[mf][nf][q] * scl);
                    }
                }
            }
        }
    }
}

// --------------------------- Aggregation --------------------------------
// One wave per node, 4 edges per gather instruction, 8 edges in flight.
// Packed f16 accumulation (v_pk_add_f16) + packed shuffle reduce.
__global__ __launch_bounds__(256) void agg_h_kernel(
        const f16* __restrict__ m, const int* __restrict__ col,
        const int* __restrict__ start, const float* __restrict__ dinv,
        const float* __restrict__ bias, f16* __restrict__ out, int N) {
    int w = (int)((blockIdx.x * 256 + threadIdx.x) >> 6);
    int lane = threadIdx.x & 63;
    if (w >= N) return;
    const int eg = lane >> 4, fl = lane & 15;
    int s = start[w], e = start[w + 1];
    f16x8 a = {}, b = {};
    int p = s;
    int end8 = s + ((e - s) & ~7);
    for (; p < end8; p += 8) {
        int j0 = col[p + eg];
        int j1 = col[p + 4 + eg];
        f16x8 v0 = *reinterpret_cast<const f16x8*>(&m[(size_t)j0 * 128 + fl * 8]);
        f16x8 v1 = *reinterpret_cast<const f16x8*>(&m[(size_t)j1 * 128 + fl * 8]);
        a += v0;
        b += v1;
    }
    if (p + 4 <= e) {
        int j = col[p + eg];
        a += *reinterpret_cast<const f16x8*>(&m[(size_t)j * 128 + fl * 8]);
        p += 4;
    }
    if (p < e) {
        int idx = p + eg;
        bool val = idx < e;
        int j = col[val ? idx : s];
        f16x8 v = *reinterpret_cast<const f16x8*>(&m[(size_t)j * 128 + fl * 8]);
        if (val) b += v;
    }
    if (eg == 0) {  // self-loop once
        a += *reinterpret_cast<const f16x8*>(&m[(size_t)w * 128 + fl * 8]);
    }
    a += b;
    pk_reduce_xor(a, 16);
    pk_reduce_xor(a, 32);
    if (eg == 0) {
        float di = dinv[w];
        float4 bA = *reinterpret_cast<const float4*>(&bias[fl * 8]);
        float4 bB = *reinterpret_cast<const float4*>(&bias[fl * 8 + 4]);
        float bb[8] = {bA.x, bA.y, bA.z, bA.w, bB.x, bB.y, bB.z, bB.w};
        f16x8 o;
#pragma unroll
        for (int u = 0; u < 8; ++u) o[u] = (f16)fmaxf(fmaf(di, (float)a[u], bb[u]), 0.f);
        *reinterpret_cast<f16x8*>(&out[(size_t)w * 128 + fl * 8]) = o;
    }
}

// Final layer: padded 64-half rows; 8 lanes x 16B per edge -> 8 edges per
// gather instruction. Packed f16 accumulate + packed reduce (8/16/32);
// classes = fl*8..fl*8+7 (fl<5 real); softmax via intra-group shuffles.
__global__ __launch_bounds__(256) void agg_out_kernel(
        const f16* __restrict__ m, const int* __restrict__ col,
        const int* __restrict__ start,
        const float* __restrict__ dinv, const float* __restrict__ bias,
        float* __restrict__ out, int N) {
    int w = (int)((blockIdx.x * 256 + threadIdx.x) >> 6);
    int lane = threadIdx.x & 63;
    if (w >= N) return;
    const int eg = lane >> 3, fl = lane & 7;
    const bool act = fl < 5;  // fl*8 .. fl*8+7 all < 40
    int s = start[w], e = start[w + 1];
    f16x8 a = {};
    int p = s;
    int end8 = s + ((e - s) & ~7);
    for (; p < end8; p += 8) {
        int j = col[p + eg];
        a += *reinterpret_cast<const f16x8*>(&m[(size_t)j * 64 + fl * 8]);
    }
    if (p < e) {
        int idx = p + eg;
        bool val = idx < e;
        int j = col[val ? idx : s];
        f16x8 v = *reinterpret_cast<const f16x8*>(&m[(size_t)j * 64 + fl * 8]);
        if (val) a += v;
    }
    if (eg == 0) {  // self-loop once
        a += *reinterpret_cast<const f16x8*>(&m[(size_t)w * 64 + fl * 8]);
    }
    pk_reduce_xor(a, 8);
    pk_reduce_xor(a, 16);
    pk_reduce_xor(a, 32);
    // bias + relu per class slot
    float di = dinv[w];
    float h[8];
    float mx = -INFINITY;
    if (act) {
        float4 bA = *reinterpret_cast<const float4*>(&bias[fl * 8]);
        float4 bB = *reinterpret_cast<const float4*>(&bias[fl * 8 + 4]);
        float bb[8] = {bA.x, bA.y, bA.z, bA.w, bB.x, bB.y, bB.z, bB.w};
#pragma unroll
        for (int u = 0; u < 8; ++u) {
            h[u] = fmaxf(fmaf(di, (float)a[u], bb[u]), 0.f);
            mx = fmaxf(mx, h[u]);
        }
    }
#pragma unroll
    for (int off = 1; off <= 4; off <<= 1) mx = fmaxf(mx, __shfl_xor(mx, off, 64));
    float se = 0.f;
    if (act) {
#pragma unroll
        for (int u = 0; u < 8; ++u) se += expf(h[u] - mx);
    }
#pragma unroll
    for (int off = 1; off <= 4; off <<= 1) se += __shfl_xor(se, off, 64);
    if (eg == 0 && act) {
        float ls = logf(se);
        float4 o0 = make_float4(h[0] - mx - ls, h[1] - mx - ls, h[2] - mx - ls, h[3] - mx - ls);
        float4 o1 = make_float4(h[4] - mx - ls, h[5] - mx - ls, h[6] - mx - ls, h[7] - mx - ls);
        *reinterpret_cast<float4*>(&out[(size_t)w * NCLASS + fl * 8]) = o0;
        *reinterpret_cast<float4*>(&out[(size_t)w * NCLASS + fl * 8 + 4]) = o1;
    }
}

// ------------------------------ launch -----------------------------------

extern "C" void kernel_launch(void* const* d_in, const int* in_sizes, int n_in,
                              void* d_out, int out_size, void* d_ws, size_t ws_size,
                              hipStream_t stream) {
    const float* x  = (const float*)d_in[0];
    const int*   ei = (const int*)d_in[1];
    const float* W0 = (const float*)d_in[2];
    const float* b0 = (const float*)d_in[3];
    const float* W1 = (const float*)d_in[4];
    const float* b1 = (const float*)d_in[5];
    const float* W2 = (const float*)d_in[6];
    const float* b2 = (const float*)d_in[7];
    float* out = (float*)d_out;

    const int NFEATr = 256;
    const int N = in_sizes[0] / NFEATr;  // 100000
    const int E = in_sizes[1] / 2;       // 1600000
    const int* src = ei;
    const int* dst = ei + E;

    const int nbuk = (N + 63) >> 6;      // 1563
    const int chunk = (E + NBLK - 1) / NBLK;

    char* p = (char*)d_ws;
    auto alloc = [&](size_t bytes) -> void* {
        void* r = (void*)p;
        p += (bytes + 255) & ~(size_t)255;
        return r;
    };
    int*    bh     = (int*)alloc((size_t)NBLK * nbuk * 4);
    int*    T      = (int*)alloc((size_t)nbuk * 4);
    int*    BB     = (int*)alloc((size_t)(nbuk + 1) * 4);
    int*    offb   = (int*)alloc((size_t)NBLK * nbuk * 4);
    int*    eb     = (int*)alloc((size_t)E * 4);
    int*    col    = (int*)alloc((size_t)E * 4);
    int*    startA = (int*)alloc((size_t)(N + 1) * 4);
    float*  dinv   = (float*)alloc((size_t)N * 4);
    f16*    mbuf   = (f16*)alloc((size_t)N * NHID * 2);
    f16*    hbuf   = (f16*)alloc((size_t)N * NHID * 2);
    f16*    m2buf  = (f16*)alloc((size_t)N * 64 * 2);   // padded 64-wide layer-2 msgs

    int nbl7 = (nbuk + 255) / 256;

    bucket_hist<<<NBLK, 256, 0, stream>>>(dst, bh, E, nbuk, chunk);
    bucket_total<<<nbl7, 256, 0, stream>>>(bh, T, nbuk);
    bucket_scan<<<1, 256, 0, stream>>>(T, BB, nbuk, E);
    bucket_expand<<<(nbuk + 3) / 4, 256, 0, stream>>>(bh, BB, offb, nbuk);
    bucket_scatter<<<NBLK, 256, 0, stream>>>(src, dst, offb, eb, E, nbuk, chunk);
    bucket_csr<<<nbuk, 256, 0, stream>>>(eb, BB, startA, dinv, col, N, E);

    int abl = (N + 3) / 4;
    int g128 = (N + 127) / 128;
    int g256 = (N + 255) / 256;

    // layer 0: x fp32 [N,256] @ W0 -> mbuf f16 (prescaled by dinv[row])
    gemm_mfma<256, 128, 128, 2, 2, false, false, 0><<<g128, 256, 0, stream>>>(
        (const void*)x, W0, dinv, mbuf, N, NHID);
    agg_h_kernel<<<abl, 256, 0, stream>>>(mbuf, col, startA, dinv, b0, hbuf, N);

    // layer 1
    gemm_mfma<128, 128, 128, 2, 2, false, true, 0><<<g128, 256, 0, stream>>>(
        (const void*)hbuf, W1, dinv, mbuf, N, NHID);
    agg_h_kernel<<<abl, 256, 0, stream>>>(mbuf, col, startA, dinv, b1, hbuf, N);

    // layer 2 (40-wide messages, padded to stride 64, pads exact zero)
    gemm_mfma<128, 256, 64, 4, 1, true, true, 64><<<g256, 256, 0, stream>>>(
        (const void*)hbuf, W2, dinv, m2buf, N, NCLASS);
    agg_out_kernel<<<abl, 256, 0, stream>>>(m2buf, col, startA, dinv, b2, out, N);
}